// Round 3
// baseline (689.434 us; speedup 1.0000x reference)
//
#include <hip/hip_runtime.h>
#include <math.h>

#define NB 8
#define TS 2048
#define DM 384
#define NH 6
#define HD 64
#define E3 1152
#define MROWS (NB*TS)

typedef __attribute__((ext_vector_type(8))) short bf16x8;
typedef __attribute__((ext_vector_type(4))) float f32x4;

__device__ __forceinline__ ushort f2bf(float f) {
    uint u = __float_as_uint(f);
    uint r = (u + 0x7FFFu + ((u >> 16) & 1u)) >> 16;
    return (ushort)r;
}
__device__ __forceinline__ float bf2f(ushort h) {
    return __uint_as_float(((uint)h) << 16);
}

#define GL_LDS16(gp, lp) \
  __builtin_amdgcn_global_load_lds((const __attribute__((address_space(1))) uint32_t*)(gp), \
                                   (__attribute__((address_space(3))) uint32_t*)(lp), 16, 0, 0)

// ---------------- RoPE cos/sin table: [T, 64] ----------------
__global__ void rope_table_k(float* __restrict__ cosT, float* __restrict__ sinT) {
    int i = blockIdx.x * 256 + threadIdx.x;
    if (i >= TS * HD) return;
    int t   = i >> 6;
    int idx = i & 63;
    int fi  = idx & 31;
    float inv = expf(-(float)fi * (logf(10000.0f) * (1.0f / 32.0f)));
    float ang = (float)t * inv;
    cosT[i] = cosf(ang);
    sinT[i] = sinf(ang);
}

// ---------------- QKV GEMM + fused RoPE + bf16 hi/lo split ----------------
// 64x64 tile. Q/K: RoPE applied (partner via shfl_xor lane^8), scale folded
// into Q, stored hi/lo bf16 [nh][T][64]. V: stored transposed [nh][64][T].
__global__ __launch_bounds__(256) void qkv_gemm_k(
    const float* __restrict__ X, const float* __restrict__ W,
    const float* __restrict__ cosT, const float* __restrict__ sinT,
    ushort* __restrict__ Qhi, ushort* __restrict__ Qlo,
    ushort* __restrict__ Khi, ushort* __restrict__ Klo,
    ushort* __restrict__ Vthi, ushort* __restrict__ Vtlo) {
    __shared__ float As[32 * 68];
    __shared__ float Bs[32 * 68];
    int tid  = threadIdx.x;
    int row0 = blockIdx.x * 64;
    int col0 = blockIdx.y * 64;
    int tr = (tid >> 4) << 2;
    int tc = (tid & 15) << 2;
    float acc[4][4] = {};

    for (int kt = 0; kt < DM; kt += 32) {
        __syncthreads();
        #pragma unroll
        for (int j = 0; j < 2; ++j) {
            int li = tid + j * 256;
            int m  = li >> 3;
            int k4 = (li & 7) << 2;
            float4 av = *(const float4*)&X[(size_t)(row0 + m) * DM + kt + k4];
            As[(k4+0)*68 + m] = av.x; As[(k4+1)*68 + m] = av.y;
            As[(k4+2)*68 + m] = av.z; As[(k4+3)*68 + m] = av.w;
            float4 bv = *(const float4*)&W[(size_t)(col0 + m) * DM + kt + k4];
            Bs[(k4+0)*68 + m] = bv.x; Bs[(k4+1)*68 + m] = bv.y;
            Bs[(k4+2)*68 + m] = bv.z; Bs[(k4+3)*68 + m] = bv.w;
        }
        __syncthreads();
        #pragma unroll
        for (int k = 0; k < 32; ++k) {
            float4 a = *(float4*)&As[k*68 + tr];
            float4 b = *(float4*)&Bs[k*68 + tc];
            acc[0][0] = fmaf(a.x, b.x, acc[0][0]); acc[0][1] = fmaf(a.x, b.y, acc[0][1]);
            acc[0][2] = fmaf(a.x, b.z, acc[0][2]); acc[0][3] = fmaf(a.x, b.w, acc[0][3]);
            acc[1][0] = fmaf(a.y, b.x, acc[1][0]); acc[1][1] = fmaf(a.y, b.y, acc[1][1]);
            acc[1][2] = fmaf(a.y, b.z, acc[1][2]); acc[1][3] = fmaf(a.y, b.w, acc[1][3]);
            acc[2][0] = fmaf(a.z, b.x, acc[2][0]); acc[2][1] = fmaf(a.z, b.y, acc[2][1]);
            acc[2][2] = fmaf(a.z, b.z, acc[2][2]); acc[2][3] = fmaf(a.z, b.w, acc[2][3]);
            acc[3][0] = fmaf(a.w, b.x, acc[3][0]); acc[3][1] = fmaf(a.w, b.y, acc[3][1]);
            acc[3][2] = fmaf(a.w, b.z, acc[3][2]); acc[3][3] = fmaf(a.w, b.w, acc[3][3]);
        }
    }
    int which = col0 / DM;               // 0=q 1=k 2=v
    int h     = (col0 % DM) >> 6;
    int n     = row0 / TS;
    int nh    = n * NH + h;

    if (which < 2) {
        ushort* dhi = (which == 0) ? Qhi : Khi;
        ushort* dlo = (which == 0) ? Qlo : Klo;
        const float qs = (which == 0) ? 0.125f : 1.0f;   // 1/sqrt(64) folded into Q
        const bool lowhalf = (tc < 32);                  // p<32 half; partner lane^8
        #pragma unroll
        for (int i = 0; i < 4; ++i) {
            int r = row0 + tr + i, t = r & (TS - 1);
            float4 cv = *(const float4*)&cosT[t * HD + tc];
            float4 sv = *(const float4*)&sinT[t * HD + tc];
            float a4[4] = {acc[i][0], acc[i][1], acc[i][2], acc[i][3]};
            float c4[4] = {cv.x, cv.y, cv.z, cv.w};
            float s4[4] = {sv.x, sv.y, sv.z, sv.w};
            ushort4 hv, lv;
            #pragma unroll
            for (int j = 0; j < 4; ++j) {
                float b = __shfl_xor(a4[j], 8);
                float v = lowhalf ? (a4[j] * c4[j] - b * s4[j])
                                  : (a4[j] * c4[j] + b * s4[j]);
                v *= qs;
                ushort hh = f2bf(v);
                ((ushort*)&hv)[j] = hh;
                ((ushort*)&lv)[j] = f2bf(v - bf2f(hh));
            }
            *(ushort4*)&dhi[((size_t)nh * TS + t) * HD + tc] = hv;
            *(ushort4*)&dlo[((size_t)nh * TS + t) * HD + tc] = lv;
        }
    } else {
        int t0 = (row0 + tr) & (TS - 1);
        #pragma unroll
        for (int j = 0; j < 4; ++j) {
            int d = tc + j;
            ushort4 hv, lv;
            #pragma unroll
            for (int i = 0; i < 4; ++i) {
                float v = acc[i][j];
                ushort hh = f2bf(v);
                ((ushort*)&hv)[i] = hh;
                ((ushort*)&lv)[i] = f2bf(v - bf2f(hh));
            }
            *(ushort4*)&Vthi[((size_t)nh * HD + d) * TS + t0] = hv;
            *(ushort4*)&Vtlo[((size_t)nh * HD + d) * TS + t0] = lv;
        }
    }
}

// ---------------- MFMA flash attention, 2-phase pipelined ----------------
// 4 waves, 128 q-rows/block, 32-key tiles, double-buffered LDS fed by
// global_load_lds (16B chunks, source pre-swizzled; LDS dest linear).
#define PSTR 52
__global__ __launch_bounds__(256) void flash_mfma_k(
    const ushort* __restrict__ Qhi, const ushort* __restrict__ Qlo,
    const ushort* __restrict__ Khi_g, const ushort* __restrict__ Klo_g,
    const ushort* __restrict__ Vthi_g, const ushort* __restrict__ Vtlo_g,
    float* __restrict__ ctx) {
    __shared__ ushort Kh[2][2048], Kl[2][2048];   // [key][d], XOR-swizzled content
    __shared__ ushort Vh[2][2048], Vl[2][2048];   // [d][key], chunk-swizzled content
    __shared__ ushort Pl[4][32 * PSTR];

    const int tid  = threadIdx.x;
    const int w    = tid >> 6;
    const int lane = tid & 63;
    const int g    = lane >> 4;
    const int c    = lane & 15;
    const int qt   = 15 - blockIdx.x;
    const int nh   = blockIdx.y;
    const int qrow0 = qt * 128 + w * 32;

    // ---- Q fragments (pre-scaled, pre-roped, hi/lo bf16) ----
    bf16x8 qh[2][2], ql[2][2];
    #pragma unroll
    for (int mf = 0; mf < 2; ++mf)
        #pragma unroll
        for (int kf = 0; kf < 2; ++kf) {
            size_t a = ((size_t)nh * TS + qrow0 + mf * 16 + c) * HD + kf * 32 + g * 8;
            qh[mf][kf] = *(const bf16x8*)&Qhi[a];
            ql[mf][kf] = *(const bf16x8*)&Qlo[a];
        }

    f32x4 o[2][4];
    float mrun[2], lrun[2];
    float mr[2][4], lr[2][4];
    #pragma unroll
    for (int mf = 0; mf < 2; ++mf) {
        #pragma unroll
        for (int nf = 0; nf < 4; ++nf) o[mf][nf] = (f32x4){0.f, 0.f, 0.f, 0.f};
        #pragma unroll
        for (int r = 0; r < 4; ++r) { mr[mf][r] = -INFINITY; lr[mf][r] = 0.f; }
    }
    (void)mrun; (void)lrun;

    // ---- staging source addresses (pre-swizzled global, linear LDS) ----
    const int kkey = tid >> 3, kcid = tid & 7;
    const ushort* khs = Khi_g + (size_t)nh * TS * HD + (size_t)kkey * HD + (((kcid ^ (kkey & 7))) << 3);
    const ushort* kls = Klo_g + (size_t)nh * TS * HD + (size_t)kkey * HD + (((kcid ^ (kkey & 7))) << 3);
    const int vd = tid >> 2, vkc = (tid & 3) ^ ((vd >> 1) & 3);
    const ushort* vhs = Vthi_g + ((size_t)nh * HD + vd) * TS + vkc * 8;
    const ushort* vls = Vtlo_g + ((size_t)nh * HD + vd) * TS + vkc * 8;
    const int ldsoff = w << 9;   // 1KB per wave (in ushorts: 512)

    const int nkt = 4 * qt + 4;
    const int wave_last = 4 * qt + w;

    #define STAGE(buf, kt) do {                                   \
        size_t ko = (size_t)(kt) * (32 * HD);                     \
        int    vo = (kt) * 32;                                    \
        GL_LDS16(khs + ko, &Kh[buf][ldsoff]);                     \
        GL_LDS16(kls + ko, &Kl[buf][ldsoff]);                     \
        GL_LDS16(vhs + vo, &Vh[buf][ldsoff]);                     \
        GL_LDS16(vls + vo, &Vl[buf][ldsoff]);                     \
    } while (0)

    STAGE(0, 0);
    __syncthreads();
    int buf = 0;

    for (int kt = 0; kt < nkt; ++kt) {
        if (kt + 1 < nkt) STAGE(buf ^ 1, kt + 1);

        if (kt <= wave_last) {
            // ---- K fragments ----
            bf16x8 khf[2][2], klf[2][2];
            #pragma unroll
            for (int nf = 0; nf < 2; ++nf)
                #pragma unroll
                for (int kf = 0; kf < 2; ++kf) {
                    int key = nf * 16 + c;
                    int off = key * 64 + ((kf * 32 + g * 8) ^ ((key & 7) << 3));
                    khf[nf][kf] = *(const bf16x8*)&Kh[buf][off];
                    klf[nf][kf] = *(const bf16x8*)&Kl[buf][off];
                }

            // ---- S = Q K^T (3-term hi/lo) ----
            f32x4 s[2][2];
            __builtin_amdgcn_s_setprio(1);
            #pragma unroll
            for (int mf = 0; mf < 2; ++mf)
                #pragma unroll
                for (int nf = 0; nf < 2; ++nf) {
                    f32x4 acc = (f32x4){0.f, 0.f, 0.f, 0.f};
                    #pragma unroll
                    for (int kf = 0; kf < 2; ++kf) {
                        acc = __builtin_amdgcn_mfma_f32_16x16x32_bf16(qh[mf][kf], khf[nf][kf], acc, 0, 0, 0);
                        acc = __builtin_amdgcn_mfma_f32_16x16x32_bf16(ql[mf][kf], khf[nf][kf], acc, 0, 0, 0);
                        acc = __builtin_amdgcn_mfma_f32_16x16x32_bf16(qh[mf][kf], klf[nf][kf], acc, 0, 0, 0);
                    }
                    s[mf][nf] = acc;
                }
            __builtin_amdgcn_s_setprio(0);

            // ---- causal mask on diagonal tile ----
            if (kt == wave_last) {
                #pragma unroll
                for (int mf = 0; mf < 2; ++mf)
                    #pragma unroll
                    for (int nf = 0; nf < 2; ++nf)
                        #pragma unroll
                        for (int r = 0; r < 4; ++r) {
                            int key = kt * 32 + nf * 16 + c;
                            int q   = qrow0 + mf * 16 + g * 4 + r;
                            if (key > q) s[mf][nf][r] = -INFINITY;
                        }
            }

            // ---- online softmax (P quantized; sum over quantized P) ----
            #pragma unroll
            for (int mf = 0; mf < 2; ++mf) {
                float tmax[4];
                #pragma unroll
                for (int r = 0; r < 4; ++r) tmax[r] = fmaxf(s[mf][0][r], s[mf][1][r]);
                #pragma unroll
                for (int d = 1; d < 16; d <<= 1)
                    #pragma unroll
                    for (int r = 0; r < 4; ++r) tmax[r] = fmaxf(tmax[r], __shfl_xor(tmax[r], d));
                float nm[4], corr[4];
                #pragma unroll
                for (int r = 0; r < 4; ++r) {
                    nm[r]   = fmaxf(mr[mf][r], tmax[r]);
                    corr[r] = __expf(mr[mf][r] - nm[r]);
                    mr[mf][r] = nm[r];
                }
                float rs[4] = {0.f, 0.f, 0.f, 0.f};
                #pragma unroll
                for (int nf = 0; nf < 2; ++nf)
                    #pragma unroll
                    for (int r = 0; r < 4; ++r) {
                        float p  = __expf(s[mf][nf][r] - nm[r]);
                        ushort ph = f2bf(p);
                        Pl[w][(mf * 16 + g * 4 + r) * PSTR + nf * 16 + c] = ph;
                        rs[r] += bf2f(ph);
                    }
                #pragma unroll
                for (int d = 1; d < 16; d <<= 1)
                    #pragma unroll
                    for (int r = 0; r < 4; ++r) rs[r] += __shfl_xor(rs[r], d);
                #pragma unroll
                for (int r = 0; r < 4; ++r) lr[mf][r] = lr[mf][r] * corr[r] + rs[r];
                #pragma unroll
                for (int nf = 0; nf < 4; ++nf)
                    #pragma unroll
                    for (int r = 0; r < 4; ++r) o[mf][nf][r] *= corr[r];
            }

            // ---- O += P V (V hi/lo from LDS) ----
            bf16x8 pa[2];
            #pragma unroll
            for (int mf = 0; mf < 2; ++mf)
                pa[mf] = *(const bf16x8*)&Pl[w][(mf * 16 + c) * PSTR + g * 8];
            bf16x8 vhf[4], vlf[4];
            #pragma unroll
            for (int nf = 0; nf < 4; ++nf) {
                int d = nf * 16 + c;
                int off = d * 32 + ((g ^ ((d >> 1) & 3)) << 3);
                vhf[nf] = *(const bf16x8*)&Vh[buf][off];
                vlf[nf] = *(const bf16x8*)&Vl[buf][off];
            }
            __builtin_amdgcn_s_setprio(1);
            #pragma unroll
            for (int mf = 0; mf < 2; ++mf)
                #pragma unroll
                for (int nf = 0; nf < 4; ++nf) {
                    o[mf][nf] = __builtin_amdgcn_mfma_f32_16x16x32_bf16(pa[mf], vhf[nf], o[mf][nf], 0, 0, 0);
                    o[mf][nf] = __builtin_amdgcn_mfma_f32_16x16x32_bf16(pa[mf], vlf[nf], o[mf][nf], 0, 0, 0);
                }
            __builtin_amdgcn_s_setprio(0);
        }

        __syncthreads();   // drains vmcnt(0): next buffer staged by all waves
        buf ^= 1;
    }

    // ---- epilogue: O / L -> ctx [N,T,D] ----
    int n = nh / NH, h = nh % NH;
    #pragma unroll
    for (int mf = 0; mf < 2; ++mf) {
        float inv[4];
        #pragma unroll
        for (int r = 0; r < 4; ++r) inv[r] = 1.0f / lr[mf][r];
        #pragma unroll
        for (int nf = 0; nf < 4; ++nf)
            #pragma unroll
            for (int r = 0; r < 4; ++r) {
                int q = qrow0 + mf * 16 + g * 4 + r;
                int d = nf * 16 + c;
                ctx[((size_t)(n * TS + q)) * DM + h * HD + d] = o[mf][nf][r] * inv[r];
            }
    }
    #undef STAGE
}

// ---------------- out projection (fp32 VALU) ----------------
__global__ __launch_bounds__(256) void outproj_gemm_k(
    const float* __restrict__ X, const float* __restrict__ W, float* __restrict__ out) {
    __shared__ float As[32 * 68];
    __shared__ float Bs[32 * 68];
    int tid  = threadIdx.x;
    int row0 = blockIdx.x * 64;
    int col0 = blockIdx.y * 64;
    int tr = (tid >> 4) << 2;
    int tc = (tid & 15) << 2;
    float acc[4][4] = {};

    for (int kt = 0; kt < DM; kt += 32) {
        __syncthreads();
        #pragma unroll
        for (int j = 0; j < 2; ++j) {
            int li = tid + j * 256;
            int m  = li >> 3;
            int k4 = (li & 7) << 2;
            float4 av = *(const float4*)&X[(size_t)(row0 + m) * DM + kt + k4];
            As[(k4+0)*68 + m] = av.x; As[(k4+1)*68 + m] = av.y;
            As[(k4+2)*68 + m] = av.z; As[(k4+3)*68 + m] = av.w;
            float4 bv = *(const float4*)&W[(size_t)(col0 + m) * DM + kt + k4];
            Bs[(k4+0)*68 + m] = bv.x; Bs[(k4+1)*68 + m] = bv.y;
            Bs[(k4+2)*68 + m] = bv.z; Bs[(k4+3)*68 + m] = bv.w;
        }
        __syncthreads();
        #pragma unroll
        for (int k = 0; k < 32; ++k) {
            float4 a = *(float4*)&As[k*68 + tr];
            float4 b = *(float4*)&Bs[k*68 + tc];
            acc[0][0] = fmaf(a.x, b.x, acc[0][0]); acc[0][1] = fmaf(a.x, b.y, acc[0][1]);
            acc[0][2] = fmaf(a.x, b.z, acc[0][2]); acc[0][3] = fmaf(a.x, b.w, acc[0][3]);
            acc[1][0] = fmaf(a.y, b.x, acc[1][0]); acc[1][1] = fmaf(a.y, b.y, acc[1][1]);
            acc[1][2] = fmaf(a.y, b.z, acc[1][2]); acc[1][3] = fmaf(a.y, b.w, acc[1][3]);
            acc[2][0] = fmaf(a.z, b.x, acc[2][0]); acc[2][1] = fmaf(a.z, b.y, acc[2][1]);
            acc[2][2] = fmaf(a.z, b.z, acc[2][2]); acc[2][3] = fmaf(a.z, b.w, acc[2][3]);
            acc[3][0] = fmaf(a.w, b.x, acc[3][0]); acc[3][1] = fmaf(a.w, b.y, acc[3][1]);
            acc[3][2] = fmaf(a.w, b.z, acc[3][2]); acc[3][3] = fmaf(a.w, b.w, acc[3][3]);
        }
    }
    #pragma unroll
    for (int i = 0; i < 4; ++i) {
        int r = row0 + tr + i;
        float4 ov = make_float4(acc[i][0], acc[i][1], acc[i][2], acc[i][3]);
        *(float4*)&out[(size_t)r * DM + col0 + tc] = ov;
    }
}

extern "C" void kernel_launch(void* const* d_in, const int* in_sizes, int n_in,
                              void* d_out, int out_size, void* d_ws, size_t ws_size,
                              hipStream_t stream) {
    const float* x    = (const float*)d_in[0];
    const float* Wqkv = (const float*)d_in[1];
    const float* Wout = (const float*)d_in[2];
    float* out = (float*)d_out;

    const size_t NHT = (size_t)NB * NH * TS * HD;   // 6.29M elements
    char* ws = (char*)d_ws;
    float* cosT = (float*)ws;                        ws += TS * HD * 4;
    float* sinT = (float*)ws;                        ws += TS * HD * 4;
    float* ctx  = (float*)ws;                        ws += (size_t)MROWS * DM * 4;
    ushort* Qhi = (ushort*)ws;                       ws += NHT * 2;
    ushort* Qlo = (ushort*)ws;                       ws += NHT * 2;
    ushort* Khi = (ushort*)ws;                       ws += NHT * 2;
    ushort* Klo = (ushort*)ws;                       ws += NHT * 2;
    ushort* Vthi = (ushort*)ws;                      ws += NHT * 2;
    ushort* Vtlo = (ushort*)ws;                      ws += NHT * 2;

    rope_table_k<<<(TS * HD) / 256, 256, 0, stream>>>(cosT, sinT);
    qkv_gemm_k<<<dim3(MROWS / 64, E3 / 64), 256, 0, stream>>>(
        x, Wqkv, cosT, sinT, Qhi, Qlo, Khi, Klo, Vthi, Vtlo);
    flash_mfma_k<<<dim3(TS / 128, NB * NH), 256, 0, stream>>>(
        Qhi, Qlo, Khi, Klo, Vthi, Vtlo, ctx);
    outproj_gemm_k<<<dim3(MROWS / 64, DM / 64), 256, 0, stream>>>(ctx, Wout, out);
}

// Round 5
// 439.868 us; speedup vs baseline: 1.5674x; 1.5674x over previous
//
#include <hip/hip_runtime.h>
#include <math.h>

#define NB 8
#define TS 2048
#define DM 384
#define NH 6
#define HD 64
#define E3 1152
#define MROWS (NB*TS)

typedef __attribute__((ext_vector_type(8))) short bf16x8;
typedef __attribute__((ext_vector_type(4))) float f32x4;

__device__ __forceinline__ ushort f2bf(float f) {
    uint u = __float_as_uint(f);
    uint r = (u + 0x7FFFu + ((u >> 16) & 1u)) >> 16;
    return (ushort)r;
}
__device__ __forceinline__ float bf2f(ushort h) {
    return __uint_as_float(((uint)h) << 16);
}

#define GL_LDS16(gp, lp) \
  __builtin_amdgcn_global_load_lds((const __attribute__((address_space(1))) uint32_t*)(gp), \
                                   (__attribute__((address_space(3))) uint32_t*)(lp), 16, 0, 0)

// ---------------- RoPE cos/sin table: [T, 64] ----------------
__global__ void rope_table_k(float* __restrict__ cosT, float* __restrict__ sinT) {
    int i = blockIdx.x * 256 + threadIdx.x;
    if (i >= TS * HD) return;
    int t   = i >> 6;
    int idx = i & 63;
    int fi  = idx & 31;
    float inv = expf(-(float)fi * (logf(10000.0f) * (1.0f / 32.0f)));
    float ang = (float)t * inv;
    cosT[i] = cosf(ang);
    sinT[i] = sinf(ang);
}

// ---------------- QKV GEMM, MFMA hi/lo, fused RoPE ----------------
// 128x64 tile, BK=64, 4 waves. A=X rows, B=Wqkv rows(=out cols), 3-term hi/lo.
// Q/K epilogue: RoPE in-register (pair nf<->nf^2), hi/lo bf16 out.
// V epilogue: LDS transpose -> Vt [nh][64][T] hi/lo.
__global__ __launch_bounds__(256) void qkv_mfma_k(
    const float* __restrict__ X, const float* __restrict__ W,
    const float* __restrict__ cosT, const float* __restrict__ sinT,
    ushort* __restrict__ Qhi, ushort* __restrict__ Qlo,
    ushort* __restrict__ Khi, ushort* __restrict__ Klo,
    ushort* __restrict__ Vthi, ushort* __restrict__ Vtlo) {
    __shared__ __align__(16) char smem[49152];
    ushort* Ah = (ushort*)smem;            // [128][64] swizzled chunks, 16KB
    ushort* Al = Ah + 128 * 64;
    ushort* Bh = Al + 128 * 64;            // [64][64], 8KB
    ushort* Bl = Bh + 64 * 64;
    float*  VT = (float*)smem;             // epilogue reuse: [64][132] f32

    const int tid  = threadIdx.x;
    const int w    = tid >> 6;
    const int lane = tid & 63;
    const int g    = lane >> 4;
    const int c    = lane & 15;
    const int row0 = blockIdx.x * 128;
    const int col0 = blockIdx.y * 64;

    f32x4 acc[2][4];
    #pragma unroll
    for (int mf = 0; mf < 2; ++mf)
        #pragma unroll
        for (int nf = 0; nf < 4; ++nf) acc[mf][nf] = (f32x4){0.f, 0.f, 0.f, 0.f};

    const int srow  = tid >> 1;            // 0..127
    const int shalf = tid & 1;             // 32-k half
    const int fra   = (srow ^ (srow >> 3)) & 7;

    for (int kt = 0; kt < 6; ++kt) {
        const int k0 = kt * 64;
        // ---- global loads (before barrier, overlap prior compute) ----
        float xv[32];
        {
            const float* xp = &X[(size_t)(row0 + srow) * DM + k0 + shalf * 32];
            #pragma unroll
            for (int j = 0; j < 8; ++j) {
                float4 t4 = *(const float4*)(xp + j * 4);
                xv[j*4+0] = t4.x; xv[j*4+1] = t4.y; xv[j*4+2] = t4.z; xv[j*4+3] = t4.w;
            }
        }
        float wv[32];
        if (tid < 128) {
            const float* wp = &W[(size_t)(col0 + srow) * DM + k0 + shalf * 32];
            #pragma unroll
            for (int j = 0; j < 8; ++j) {
                float4 t4 = *(const float4*)(wp + j * 4);
                wv[j*4+0] = t4.x; wv[j*4+1] = t4.y; wv[j*4+2] = t4.z; wv[j*4+3] = t4.w;
            }
        }
        __syncthreads();
        // ---- convert + swizzled LDS writes ----
        #pragma unroll
        for (int ch4 = 0; ch4 < 4; ++ch4) {
            bf16x8 hv, lv;
            #pragma unroll
            for (int e = 0; e < 8; ++e) {
                float f = xv[ch4 * 8 + e];
                ushort h = f2bf(f);
                hv[e] = (short)h;
                lv[e] = (short)f2bf(f - bf2f(h));
            }
            int off = srow * 64 + (((shalf * 4 + ch4) ^ fra) << 3);
            *(bf16x8*)&Ah[off] = hv;
            *(bf16x8*)&Al[off] = lv;
        }
        if (tid < 128) {
            #pragma unroll
            for (int ch4 = 0; ch4 < 4; ++ch4) {
                bf16x8 hv, lv;
                #pragma unroll
                for (int e = 0; e < 8; ++e) {
                    float f = wv[ch4 * 8 + e];
                    ushort h = f2bf(f);
                    hv[e] = (short)h;
                    lv[e] = (short)f2bf(f - bf2f(h));
                }
                int off = srow * 64 + (((shalf * 4 + ch4) ^ fra) << 3);
                *(bf16x8*)&Bh[off] = hv;
                *(bf16x8*)&Bl[off] = lv;
            }
        }
        __syncthreads();
        // ---- fragments ----
        bf16x8 ahf[2][2], alf[2][2], bhf[4][2], blf[4][2];
        #pragma unroll
        for (int mf = 0; mf < 2; ++mf) {
            int arow = w * 32 + mf * 16 + c;
            int fa = (arow ^ (arow >> 3)) & 7;
            #pragma unroll
            for (int kf = 0; kf < 2; ++kf) {
                int off = arow * 64 + (((kf * 4 + g) ^ fa) << 3);
                ahf[mf][kf] = *(const bf16x8*)&Ah[off];
                alf[mf][kf] = *(const bf16x8*)&Al[off];
            }
        }
        #pragma unroll
        for (int nf = 0; nf < 4; ++nf) {
            int brow = nf * 16 + c;
            int fb = (brow ^ (brow >> 3)) & 7;
            #pragma unroll
            for (int kf = 0; kf < 2; ++kf) {
                int off = brow * 64 + (((kf * 4 + g) ^ fb) << 3);
                bhf[nf][kf] = *(const bf16x8*)&Bh[off];
                blf[nf][kf] = *(const bf16x8*)&Bl[off];
            }
        }
        __builtin_amdgcn_s_setprio(1);
        #pragma unroll
        for (int mf = 0; mf < 2; ++mf)
            #pragma unroll
            for (int nf = 0; nf < 4; ++nf)
                #pragma unroll
                for (int kf = 0; kf < 2; ++kf) {
                    acc[mf][nf] = __builtin_amdgcn_mfma_f32_16x16x32_bf16(ahf[mf][kf], bhf[nf][kf], acc[mf][nf], 0, 0, 0);
                    acc[mf][nf] = __builtin_amdgcn_mfma_f32_16x16x32_bf16(alf[mf][kf], bhf[nf][kf], acc[mf][nf], 0, 0, 0);
                    acc[mf][nf] = __builtin_amdgcn_mfma_f32_16x16x32_bf16(ahf[mf][kf], blf[nf][kf], acc[mf][nf], 0, 0, 0);
                }
        __builtin_amdgcn_s_setprio(0);
    }

    const int which = blockIdx.y / 6;      // 0=q 1=k 2=v
    const int hh    = blockIdx.y % 6;
    const int n     = row0 >> 11;
    const int nh    = n * NH + hh;

    if (which < 2) {
        ushort* dhi = (which == 0) ? Qhi : Khi;
        ushort* dlo = (which == 0) ? Qlo : Klo;
        const float qs = (which == 0) ? 0.125f : 1.0f;
        #pragma unroll
        for (int mf = 0; mf < 2; ++mf)
            #pragma unroll
            for (int r = 0; r < 4; ++r) {
                int t = (row0 + w * 32 + mf * 16 + 4 * g + r) & (TS - 1);
                #pragma unroll
                for (int nf = 0; nf < 4; ++nf) {
                    int p = nf * 16 + c;
                    float a = acc[mf][nf][r];
                    float b = acc[mf][nf ^ 2][r];
                    float cc = cosT[t * HD + p];
                    float ss = sinT[t * HD + p];
                    float v = (nf < 2) ? (a * cc - b * ss) : (a * cc + b * ss);
                    v *= qs;
                    ushort h = f2bf(v);
                    size_t addr = ((size_t)nh * TS + t) * HD + p;
                    dhi[addr] = h;
                    dlo[addr] = f2bf(v - bf2f(h));
                }
            }
    } else {
        __syncthreads();                    // staging LDS done; reuse as VT
        #pragma unroll
        for (int mf = 0; mf < 2; ++mf)
            #pragma unroll
            for (int nf = 0; nf < 4; ++nf)
                #pragma unroll
                for (int r = 0; r < 4; ++r)
                    VT[(nf * 16 + c) * 132 + w * 32 + mf * 16 + 4 * g + r] = acc[mf][nf][r];
        __syncthreads();
        int d = tid >> 2, seg = (tid & 3) * 32;
        int t0 = row0 & (TS - 1);
        size_t vbase = ((size_t)nh * HD + d) * TS + t0 + seg;
        #pragma unroll
        for (int j = 0; j < 4; ++j) {
            bf16x8 hv, lv;
            #pragma unroll
            for (int e = 0; e < 8; ++e) {
                float f = VT[d * 132 + seg + j * 8 + e];
                ushort h = f2bf(f);
                hv[e] = (short)h;
                lv[e] = (short)f2bf(f - bf2f(h));
            }
            *(bf16x8*)&Vthi[vbase + j * 8] = hv;
            *(bf16x8*)&Vtlo[vbase + j * 8] = lv;
        }
    }
}

// ---------------- MFMA flash attention, balanced q-tile pairs ----------------
// Grid 384: xcd=b&7 owns 6 nh's; block runs qtA=15-p then qtB=p (68 steps each).
#define PSTR 52
__global__ __launch_bounds__(256) void flash_mfma_k(
    const ushort* __restrict__ Qhi, const ushort* __restrict__ Qlo,
    const ushort* __restrict__ Khi_g, const ushort* __restrict__ Klo_g,
    const ushort* __restrict__ Vthi_g, const ushort* __restrict__ Vtlo_g,
    ushort* __restrict__ ctxhi, ushort* __restrict__ ctxlo) {
    __shared__ ushort Kh[2][2048], Kl[2][2048];
    __shared__ ushort Vh[2][2048], Vl[2][2048];
    __shared__ ushort Pl[4][32 * PSTR];

    const int tid  = threadIdx.x;
    const int w    = tid >> 6;
    const int lane = tid & 63;
    const int g    = lane >> 4;
    const int c    = lane & 15;

    const int b   = blockIdx.x;
    const int xcd = b & 7;
    const int li  = b >> 3;
    const int nh  = xcd * 6 + li / 8;
    const int pr  = li % 8;
    const int qtA = 15 - pr, qtB = pr;

    // ---- staging addresses (phase-independent) ----
    const int kkey = tid >> 3, kcid = tid & 7;
    const ushort* khs = Khi_g + (size_t)nh * TS * HD + (size_t)kkey * HD + ((kcid ^ (kkey & 7)) << 3);
    const ushort* kls = Klo_g + (size_t)nh * TS * HD + (size_t)kkey * HD + ((kcid ^ (kkey & 7)) << 3);
    const int vd = tid >> 2, vkc = (tid & 3) ^ ((vd >> 1) & 3);
    const ushort* vhs = Vthi_g + ((size_t)nh * HD + vd) * TS + vkc * 8;
    const ushort* vls = Vtlo_g + ((size_t)nh * HD + vd) * TS + vkc * 8;
    const int ldsoff = w << 9;

    #define STAGE(buf, kt) do {                                   \
        size_t ko = (size_t)(kt) * (32 * HD);                     \
        int    vo = (kt) * 32;                                    \
        GL_LDS16(khs + ko, &Kh[buf][ldsoff]);                     \
        GL_LDS16(kls + ko, &Kl[buf][ldsoff]);                     \
        GL_LDS16(vhs + vo, &Vh[buf][ldsoff]);                     \
        GL_LDS16(vls + vo, &Vl[buf][ldsoff]);                     \
    } while (0)

    const int n2 = nh / NH, hh2 = nh % NH;

    for (int ph = 0; ph < 2; ++ph) {
        const int qt = ph ? qtB : qtA;
        const int qrow0 = qt * 128 + w * 32;
        const int nkt = 4 * qt + 4;
        const int wave_last = 4 * qt + w;

        // ---- Q fragments ----
        bf16x8 qh[2][2], ql[2][2];
        #pragma unroll
        for (int mf = 0; mf < 2; ++mf)
            #pragma unroll
            for (int kf = 0; kf < 2; ++kf) {
                size_t a = ((size_t)nh * TS + qrow0 + mf * 16 + c) * HD + kf * 32 + g * 8;
                qh[mf][kf] = *(const bf16x8*)&Qhi[a];
                ql[mf][kf] = *(const bf16x8*)&Qlo[a];
            }

        f32x4 o[2][4];
        float mr[2][4], lr[2][4];
        #pragma unroll
        for (int mf = 0; mf < 2; ++mf) {
            #pragma unroll
            for (int nf = 0; nf < 4; ++nf) o[mf][nf] = (f32x4){0.f, 0.f, 0.f, 0.f};
            #pragma unroll
            for (int r = 0; r < 4; ++r) { mr[mf][r] = -INFINITY; lr[mf][r] = 0.f; }
        }

        STAGE(0, 0);
        __syncthreads();
        int buf = 0;

        for (int kt = 0; kt < nkt; ++kt) {
            if (kt + 1 < nkt) STAGE(buf ^ 1, kt + 1);

            if (kt <= wave_last) {
                bf16x8 khf[2][2], klf[2][2];
                #pragma unroll
                for (int nf = 0; nf < 2; ++nf)
                    #pragma unroll
                    for (int kf = 0; kf < 2; ++kf) {
                        int key = nf * 16 + c;
                        int off = key * 64 + ((kf * 32 + g * 8) ^ ((key & 7) << 3));
                        khf[nf][kf] = *(const bf16x8*)&Kh[buf][off];
                        klf[nf][kf] = *(const bf16x8*)&Kl[buf][off];
                    }

                f32x4 s[2][2];
                __builtin_amdgcn_s_setprio(1);
                #pragma unroll
                for (int mf = 0; mf < 2; ++mf)
                    #pragma unroll
                    for (int nf = 0; nf < 2; ++nf) {
                        f32x4 a2 = (f32x4){0.f, 0.f, 0.f, 0.f};
                        #pragma unroll
                        for (int kf = 0; kf < 2; ++kf) {
                            a2 = __builtin_amdgcn_mfma_f32_16x16x32_bf16(qh[mf][kf], khf[nf][kf], a2, 0, 0, 0);
                            a2 = __builtin_amdgcn_mfma_f32_16x16x32_bf16(ql[mf][kf], khf[nf][kf], a2, 0, 0, 0);
                            a2 = __builtin_amdgcn_mfma_f32_16x16x32_bf16(qh[mf][kf], klf[nf][kf], a2, 0, 0, 0);
                        }
                        s[mf][nf] = a2;
                    }
                __builtin_amdgcn_s_setprio(0);

                if (kt == wave_last) {
                    #pragma unroll
                    for (int mf = 0; mf < 2; ++mf)
                        #pragma unroll
                        for (int nf = 0; nf < 2; ++nf)
                            #pragma unroll
                            for (int r = 0; r < 4; ++r) {
                                int key = kt * 32 + nf * 16 + c;
                                int q   = qrow0 + mf * 16 + g * 4 + r;
                                if (key > q) s[mf][nf][r] = -INFINITY;
                            }
                }

                #pragma unroll
                for (int mf = 0; mf < 2; ++mf) {
                    float tmax[4];
                    #pragma unroll
                    for (int r = 0; r < 4; ++r) tmax[r] = fmaxf(s[mf][0][r], s[mf][1][r]);
                    #pragma unroll
                    for (int d = 1; d < 16; d <<= 1)
                        #pragma unroll
                        for (int r = 0; r < 4; ++r) tmax[r] = fmaxf(tmax[r], __shfl_xor(tmax[r], d));
                    float nm[4], corr[4];
                    #pragma unroll
                    for (int r = 0; r < 4; ++r) {
                        nm[r]   = fmaxf(mr[mf][r], tmax[r]);
                        corr[r] = __expf(mr[mf][r] - nm[r]);
                        mr[mf][r] = nm[r];
                    }
                    float rs[4] = {0.f, 0.f, 0.f, 0.f};
                    #pragma unroll
                    for (int nf = 0; nf < 2; ++nf)
                        #pragma unroll
                        for (int r = 0; r < 4; ++r) {
                            float p  = __expf(s[mf][nf][r] - nm[r]);
                            ushort phq = f2bf(p);
                            Pl[w][(mf * 16 + g * 4 + r) * PSTR + nf * 16 + c] = phq;
                            rs[r] += bf2f(phq);
                        }
                    #pragma unroll
                    for (int d = 1; d < 16; d <<= 1)
                        #pragma unroll
                        for (int r = 0; r < 4; ++r) rs[r] += __shfl_xor(rs[r], d);
                    #pragma unroll
                    for (int r = 0; r < 4; ++r) lr[mf][r] = lr[mf][r] * corr[r] + rs[r];
                    #pragma unroll
                    for (int nf = 0; nf < 4; ++nf)
                        #pragma unroll
                        for (int r = 0; r < 4; ++r) o[mf][nf][r] *= corr[r];
                }

                bf16x8 pa[2];
                #pragma unroll
                for (int mf = 0; mf < 2; ++mf)
                    pa[mf] = *(const bf16x8*)&Pl[w][(mf * 16 + c) * PSTR + g * 8];
                bf16x8 vhf[4], vlf[4];
                #pragma unroll
                for (int nf = 0; nf < 4; ++nf) {
                    int d = nf * 16 + c;
                    int off = d * 32 + ((g ^ ((d >> 1) & 3)) << 3);
                    vhf[nf] = *(const bf16x8*)&Vh[buf][off];
                    vlf[nf] = *(const bf16x8*)&Vl[buf][off];
                }
                __builtin_amdgcn_s_setprio(1);
                #pragma unroll
                for (int mf = 0; mf < 2; ++mf)
                    #pragma unroll
                    for (int nf = 0; nf < 4; ++nf) {
                        o[mf][nf] = __builtin_amdgcn_mfma_f32_16x16x32_bf16(pa[mf], vhf[nf], o[mf][nf], 0, 0, 0);
                        o[mf][nf] = __builtin_amdgcn_mfma_f32_16x16x32_bf16(pa[mf], vlf[nf], o[mf][nf], 0, 0, 0);
                    }
                __builtin_amdgcn_s_setprio(0);
            }

            __syncthreads();
            buf ^= 1;
        }

        // ---- epilogue: O/L -> ctx hi/lo bf16 [N,T,D] ----
        #pragma unroll
        for (int mf = 0; mf < 2; ++mf) {
            float inv[4];
            #pragma unroll
            for (int r = 0; r < 4; ++r) inv[r] = 1.0f / lr[mf][r];
            #pragma unroll
            for (int nf = 0; nf < 4; ++nf)
                #pragma unroll
                for (int r = 0; r < 4; ++r) {
                    int q = qrow0 + mf * 16 + g * 4 + r;
                    int d = nf * 16 + c;
                    float v = o[mf][nf][r] * inv[r];
                    ushort h = f2bf(v);
                    size_t a = ((size_t)(n2 * TS + q)) * DM + hh2 * HD + d;
                    ctxhi[a] = h;
                    ctxlo[a] = f2bf(v - bf2f(h));
                }
        }
    }
    #undef STAGE
}

// ---------------- out projection, MFMA hi/lo ----------------
// A = ctx (pre-split bf16 hi/lo), B = Wout (fp32, convert in-kernel).
__global__ __launch_bounds__(256) void outproj_mfma_k(
    const ushort* __restrict__ Ahi_g, const ushort* __restrict__ Alo_g,
    const float* __restrict__ W, float* __restrict__ out) {
    __shared__ __align__(16) char smem[49152];
    ushort* Ah = (ushort*)smem;
    ushort* Al = Ah + 128 * 64;
    ushort* Bh = Al + 128 * 64;
    ushort* Bl = Bh + 64 * 64;

    const int tid  = threadIdx.x;
    const int w    = tid >> 6;
    const int lane = tid & 63;
    const int g    = lane >> 4;
    const int c    = lane & 15;
    const int row0 = blockIdx.x * 128;
    const int col0 = blockIdx.y * 64;

    f32x4 acc[2][4];
    #pragma unroll
    for (int mf = 0; mf < 2; ++mf)
        #pragma unroll
        for (int nf = 0; nf < 4; ++nf) acc[mf][nf] = (f32x4){0.f, 0.f, 0.f, 0.f};

    const int srow  = tid >> 1;
    const int shalf = tid & 1;
    const int fra   = (srow ^ (srow >> 3)) & 7;

    for (int kt = 0; kt < 6; ++kt) {
        const int k0 = kt * 64;
        bf16x8 ahv[4], alv[4];
        {
            const ushort* ap = &Ahi_g[(size_t)(row0 + srow) * DM + k0 + shalf * 32];
            const ushort* lp = &Alo_g[(size_t)(row0 + srow) * DM + k0 + shalf * 32];
            #pragma unroll
            for (int j = 0; j < 4; ++j) {
                ahv[j] = *(const bf16x8*)(ap + j * 8);
                alv[j] = *(const bf16x8*)(lp + j * 8);
            }
        }
        float wv[32];
        if (tid < 128) {
            const float* wp = &W[(size_t)(col0 + srow) * DM + k0 + shalf * 32];
            #pragma unroll
            for (int j = 0; j < 8; ++j) {
                float4 t4 = *(const float4*)(wp + j * 4);
                wv[j*4+0] = t4.x; wv[j*4+1] = t4.y; wv[j*4+2] = t4.z; wv[j*4+3] = t4.w;
            }
        }
        __syncthreads();
        #pragma unroll
        for (int j = 0; j < 4; ++j) {
            int off = srow * 64 + (((shalf * 4 + j) ^ fra) << 3);
            *(bf16x8*)&Ah[off] = ahv[j];
            *(bf16x8*)&Al[off] = alv[j];
        }
        if (tid < 128) {
            #pragma unroll
            for (int ch4 = 0; ch4 < 4; ++ch4) {
                bf16x8 hv, lv;
                #pragma unroll
                for (int e = 0; e < 8; ++e) {
                    float f = wv[ch4 * 8 + e];
                    ushort h = f2bf(f);
                    hv[e] = (short)h;
                    lv[e] = (short)f2bf(f - bf2f(h));
                }
                int off = srow * 64 + (((shalf * 4 + ch4) ^ fra) << 3);
                *(bf16x8*)&Bh[off] = hv;
                *(bf16x8*)&Bl[off] = lv;
            }
        }
        __syncthreads();
        bf16x8 ahf[2][2], alf[2][2], bhf[4][2], blf[4][2];
        #pragma unroll
        for (int mf = 0; mf < 2; ++mf) {
            int arow = w * 32 + mf * 16 + c;
            int fa = (arow ^ (arow >> 3)) & 7;
            #pragma unroll
            for (int kf = 0; kf < 2; ++kf) {
                int off = arow * 64 + (((kf * 4 + g) ^ fa) << 3);
                ahf[mf][kf] = *(const bf16x8*)&Ah[off];
                alf[mf][kf] = *(const bf16x8*)&Al[off];
            }
        }
        #pragma unroll
        for (int nf = 0; nf < 4; ++nf) {
            int brow = nf * 16 + c;
            int fb = (brow ^ (brow >> 3)) & 7;
            #pragma unroll
            for (int kf = 0; kf < 2; ++kf) {
                int off = brow * 64 + (((kf * 4 + g) ^ fb) << 3);
                bhf[nf][kf] = *(const bf16x8*)&Bh[off];
                blf[nf][kf] = *(const bf16x8*)&Bl[off];
            }
        }
        __builtin_amdgcn_s_setprio(1);
        #pragma unroll
        for (int mf = 0; mf < 2; ++mf)
            #pragma unroll
            for (int nf = 0; nf < 4; ++nf)
                #pragma unroll
                for (int kf = 0; kf < 2; ++kf) {
                    acc[mf][nf] = __builtin_amdgcn_mfma_f32_16x16x32_bf16(ahf[mf][kf], bhf[nf][kf], acc[mf][nf], 0, 0, 0);
                    acc[mf][nf] = __builtin_amdgcn_mfma_f32_16x16x32_bf16(alf[mf][kf], bhf[nf][kf], acc[mf][nf], 0, 0, 0);
                    acc[mf][nf] = __builtin_amdgcn_mfma_f32_16x16x32_bf16(ahf[mf][kf], blf[nf][kf], acc[mf][nf], 0, 0, 0);
                }
        __builtin_amdgcn_s_setprio(0);
    }

    #pragma unroll
    for (int mf = 0; mf < 2; ++mf)
        #pragma unroll
        for (int r = 0; r < 4; ++r) {
            int row = row0 + w * 32 + mf * 16 + 4 * g + r;
            #pragma unroll
            for (int nf = 0; nf < 4; ++nf)
                out[(size_t)row * DM + col0 + nf * 16 + c] = acc[mf][nf][r];
        }
}

extern "C" void kernel_launch(void* const* d_in, const int* in_sizes, int n_in,
                              void* d_out, int out_size, void* d_ws, size_t ws_size,
                              hipStream_t stream) {
    const float* x    = (const float*)d_in[0];
    const float* Wqkv = (const float*)d_in[1];
    const float* Wout = (const float*)d_in[2];
    float* out = (float*)d_out;

    const size_t NHT = (size_t)NB * NH * TS * HD;
    char* ws = (char*)d_ws;
    float* cosT = (float*)ws;                        ws += TS * HD * 4;
    float* sinT = (float*)ws;                        ws += TS * HD * 4;
    ushort* Qhi = (ushort*)ws;                       ws += NHT * 2;
    ushort* Qlo = (ushort*)ws;                       ws += NHT * 2;
    ushort* Khi = (ushort*)ws;                       ws += NHT * 2;
    ushort* Klo = (ushort*)ws;                       ws += NHT * 2;
    ushort* Vthi = (ushort*)ws;                      ws += NHT * 2;
    ushort* Vtlo = (ushort*)ws;                      ws += NHT * 2;
    ushort* ctxhi = (ushort*)ws;                     ws += (size_t)MROWS * DM * 2;
    ushort* ctxlo = (ushort*)ws;                     ws += (size_t)MROWS * DM * 2;

    rope_table_k<<<(TS * HD) / 256, 256, 0, stream>>>(cosT, sinT);
    qkv_mfma_k<<<dim3(MROWS / 128, E3 / 64), 256, 0, stream>>>(
        x, Wqkv, cosT, sinT, Qhi, Qlo, Khi, Klo, Vthi, Vtlo);
    flash_mfma_k<<<384, 256, 0, stream>>>(
        Qhi, Qlo, Khi, Klo, Vthi, Vtlo, ctxhi, ctxlo);
    outproj_mfma_k<<<dim3(MROWS / 128, DM / 64), 256, 0, stream>>>(
        ctxhi, ctxlo, Wout, out);
}

// Round 6
// 372.810 us; speedup vs baseline: 1.8493x; 1.1799x over previous
//
#include <hip/hip_runtime.h>
#include <math.h>

#define NB 8
#define TS 2048
#define DM 384
#define NH 6
#define HD 64
#define E3 1152
#define MROWS (NB*TS)

typedef __attribute__((ext_vector_type(8))) short bf16x8;
typedef __attribute__((ext_vector_type(4))) float f32x4;

__device__ __forceinline__ ushort f2bf(float f) {
    uint u = __float_as_uint(f);
    uint r = (u + 0x7FFFu + ((u >> 16) & 1u)) >> 16;
    return (ushort)r;
}
__device__ __forceinline__ float bf2f(ushort h) {
    return __uint_as_float(((uint)h) << 16);
}

#define GL_LDS16(gp, lp) \
  __builtin_amdgcn_global_load_lds((const __attribute__((address_space(1))) uint32_t*)(gp), \
                                   (__attribute__((address_space(3))) uint32_t*)(lp), 16, 0, 0)

// ---------------- RoPE cos/sin table: [T, 64] ----------------
__global__ void rope_table_k(float* __restrict__ cosT, float* __restrict__ sinT) {
    int i = blockIdx.x * 256 + threadIdx.x;
    if (i >= TS * HD) return;
    int t   = i >> 6;
    int idx = i & 63;
    int fi  = idx & 31;
    float inv = expf(-(float)fi * (logf(10000.0f) * (1.0f / 32.0f)));
    float ang = (float)t * inv;
    cosT[i] = cosf(ang);
    sinT[i] = sinf(ang);
}

// ---------------- QKV GEMM, MFMA hi/lo, fused RoPE (unchanged r5) ----------------
__global__ __launch_bounds__(256) void qkv_mfma_k(
    const float* __restrict__ X, const float* __restrict__ W,
    const float* __restrict__ cosT, const float* __restrict__ sinT,
    ushort* __restrict__ Qhi, ushort* __restrict__ Qlo,
    ushort* __restrict__ Khi, ushort* __restrict__ Klo,
    ushort* __restrict__ Vthi, ushort* __restrict__ Vtlo) {
    __shared__ __align__(16) char smem[49152];
    ushort* Ah = (ushort*)smem;
    ushort* Al = Ah + 128 * 64;
    ushort* Bh = Al + 128 * 64;
    ushort* Bl = Bh + 64 * 64;
    float*  VT = (float*)smem;

    const int tid  = threadIdx.x;
    const int w    = tid >> 6;
    const int lane = tid & 63;
    const int g    = lane >> 4;
    const int c    = lane & 15;
    const int row0 = blockIdx.x * 128;
    const int col0 = blockIdx.y * 64;

    f32x4 acc[2][4];
    #pragma unroll
    for (int mf = 0; mf < 2; ++mf)
        #pragma unroll
        for (int nf = 0; nf < 4; ++nf) acc[mf][nf] = (f32x4){0.f, 0.f, 0.f, 0.f};

    const int srow  = tid >> 1;
    const int shalf = tid & 1;
    const int fra   = (srow ^ (srow >> 3)) & 7;

    for (int kt = 0; kt < 6; ++kt) {
        const int k0 = kt * 64;
        float xv[32];
        {
            const float* xp = &X[(size_t)(row0 + srow) * DM + k0 + shalf * 32];
            #pragma unroll
            for (int j = 0; j < 8; ++j) {
                float4 t4 = *(const float4*)(xp + j * 4);
                xv[j*4+0] = t4.x; xv[j*4+1] = t4.y; xv[j*4+2] = t4.z; xv[j*4+3] = t4.w;
            }
        }
        float wv[32];
        if (tid < 128) {
            const float* wp = &W[(size_t)(col0 + srow) * DM + k0 + shalf * 32];
            #pragma unroll
            for (int j = 0; j < 8; ++j) {
                float4 t4 = *(const float4*)(wp + j * 4);
                wv[j*4+0] = t4.x; wv[j*4+1] = t4.y; wv[j*4+2] = t4.z; wv[j*4+3] = t4.w;
            }
        }
        __syncthreads();
        #pragma unroll
        for (int ch4 = 0; ch4 < 4; ++ch4) {
            bf16x8 hv, lv;
            #pragma unroll
            for (int e = 0; e < 8; ++e) {
                float f = xv[ch4 * 8 + e];
                ushort h = f2bf(f);
                hv[e] = (short)h;
                lv[e] = (short)f2bf(f - bf2f(h));
            }
            int off = srow * 64 + (((shalf * 4 + ch4) ^ fra) << 3);
            *(bf16x8*)&Ah[off] = hv;
            *(bf16x8*)&Al[off] = lv;
        }
        if (tid < 128) {
            #pragma unroll
            for (int ch4 = 0; ch4 < 4; ++ch4) {
                bf16x8 hv, lv;
                #pragma unroll
                for (int e = 0; e < 8; ++e) {
                    float f = wv[ch4 * 8 + e];
                    ushort h = f2bf(f);
                    hv[e] = (short)h;
                    lv[e] = (short)f2bf(f - bf2f(h));
                }
                int off = srow * 64 + (((shalf * 4 + ch4) ^ fra) << 3);
                *(bf16x8*)&Bh[off] = hv;
                *(bf16x8*)&Bl[off] = lv;
            }
        }
        __syncthreads();
        bf16x8 ahf[2][2], alf[2][2], bhf[4][2], blf[4][2];
        #pragma unroll
        for (int mf = 0; mf < 2; ++mf) {
            int arow = w * 32 + mf * 16 + c;
            int fa = (arow ^ (arow >> 3)) & 7;
            #pragma unroll
            for (int kf = 0; kf < 2; ++kf) {
                int off = arow * 64 + (((kf * 4 + g) ^ fa) << 3);
                ahf[mf][kf] = *(const bf16x8*)&Ah[off];
                alf[mf][kf] = *(const bf16x8*)&Al[off];
            }
        }
        #pragma unroll
        for (int nf = 0; nf < 4; ++nf) {
            int brow = nf * 16 + c;
            int fb = (brow ^ (brow >> 3)) & 7;
            #pragma unroll
            for (int kf = 0; kf < 2; ++kf) {
                int off = brow * 64 + (((kf * 4 + g) ^ fb) << 3);
                bhf[nf][kf] = *(const bf16x8*)&Bh[off];
                blf[nf][kf] = *(const bf16x8*)&Bl[off];
            }
        }
        __builtin_amdgcn_s_setprio(1);
        #pragma unroll
        for (int mf = 0; mf < 2; ++mf)
            #pragma unroll
            for (int nf = 0; nf < 4; ++nf)
                #pragma unroll
                for (int kf = 0; kf < 2; ++kf) {
                    acc[mf][nf] = __builtin_amdgcn_mfma_f32_16x16x32_bf16(ahf[mf][kf], bhf[nf][kf], acc[mf][nf], 0, 0, 0);
                    acc[mf][nf] = __builtin_amdgcn_mfma_f32_16x16x32_bf16(alf[mf][kf], bhf[nf][kf], acc[mf][nf], 0, 0, 0);
                    acc[mf][nf] = __builtin_amdgcn_mfma_f32_16x16x32_bf16(ahf[mf][kf], blf[nf][kf], acc[mf][nf], 0, 0, 0);
                }
        __builtin_amdgcn_s_setprio(0);
    }

    const int which = blockIdx.y / 6;
    const int hh    = blockIdx.y % 6;
    const int n     = row0 >> 11;
    const int nh    = n * NH + hh;

    if (which < 2) {
        ushort* dhi = (which == 0) ? Qhi : Khi;
        ushort* dlo = (which == 0) ? Qlo : Klo;
        const float qs = (which == 0) ? 0.125f : 1.0f;
        #pragma unroll
        for (int mf = 0; mf < 2; ++mf)
            #pragma unroll
            for (int r = 0; r < 4; ++r) {
                int t = (row0 + w * 32 + mf * 16 + 4 * g + r) & (TS - 1);
                #pragma unroll
                for (int nf = 0; nf < 4; ++nf) {
                    int p = nf * 16 + c;
                    float a = acc[mf][nf][r];
                    float b = acc[mf][nf ^ 2][r];
                    float cc = cosT[t * HD + p];
                    float ss = sinT[t * HD + p];
                    float v = (nf < 2) ? (a * cc - b * ss) : (a * cc + b * ss);
                    v *= qs;
                    ushort h = f2bf(v);
                    size_t addr = ((size_t)nh * TS + t) * HD + p;
                    dhi[addr] = h;
                    dlo[addr] = f2bf(v - bf2f(h));
                }
            }
    } else {
        __syncthreads();
        #pragma unroll
        for (int mf = 0; mf < 2; ++mf)
            #pragma unroll
            for (int nf = 0; nf < 4; ++nf)
                #pragma unroll
                for (int r = 0; r < 4; ++r)
                    VT[(nf * 16 + c) * 132 + w * 32 + mf * 16 + 4 * g + r] = acc[mf][nf][r];
        __syncthreads();
        int d = tid >> 2, seg = (tid & 3) * 32;
        int t0 = row0 & (TS - 1);
        size_t vbase = ((size_t)nh * HD + d) * TS + t0 + seg;
        #pragma unroll
        for (int j = 0; j < 4; ++j) {
            bf16x8 hv, lv;
            #pragma unroll
            for (int e = 0; e < 8; ++e) {
                float f = VT[d * 132 + seg + j * 8 + e];
                ushort h = f2bf(f);
                hv[e] = (short)h;
                lv[e] = (short)f2bf(f - bf2f(h));
            }
            *(bf16x8*)&Vthi[vbase + j * 8] = hv;
            *(bf16x8*)&Vtlo[vbase + j * 8] = lv;
        }
    }
}

// ---------------- MFMA flash attention, swapped-operand softmax ----------------
// S^T = mfma(K,Q): each lane owns q = c (+16mf) => row stats are per-lane
// scalars; max/sum = 7 in-reg ops + 2-level shfl. O^T = mfma(Vt, P^T).
// P^T->B-frag relayout via tiny LDS bounce (4 words/lane, bijective).
__global__ __launch_bounds__(256) void flash_mfma_k(
    const ushort* __restrict__ Qhi, const ushort* __restrict__ Qlo,
    const ushort* __restrict__ Khi_g, const ushort* __restrict__ Klo_g,
    const ushort* __restrict__ Vthi_g, const ushort* __restrict__ Vtlo_g,
    ushort* __restrict__ ctxhi, ushort* __restrict__ ctxlo) {
    __shared__ ushort Kh[2][2048], Kl[2][2048];
    __shared__ ushort Vh[2][2048], Vl[2][2048];
    __shared__ uint   Pw[4][2][320];   // [wave][mf][16 q * 20]

    const int tid  = threadIdx.x;
    const int w    = tid >> 6;
    const int lane = tid & 63;
    const int g    = lane >> 4;
    const int c    = lane & 15;

    const int b   = blockIdx.x;
    const int xcd = b & 7;
    const int li  = b >> 3;
    const int nh  = xcd * 6 + li / 8;
    const int pr  = li % 8;
    const int qtA = 15 - pr, qtB = pr;

    const int kkey = tid >> 3, kcid = tid & 7;
    const ushort* khs = Khi_g + (size_t)nh * TS * HD + (size_t)kkey * HD + ((kcid ^ (kkey & 7)) << 3);
    const ushort* kls = Klo_g + (size_t)nh * TS * HD + (size_t)kkey * HD + ((kcid ^ (kkey & 7)) << 3);
    const int vd = tid >> 2, vkc = (tid & 3) ^ ((vd >> 1) & 3);
    const ushort* vhs = Vthi_g + ((size_t)nh * HD + vd) * TS + vkc * 8;
    const ushort* vls = Vtlo_g + ((size_t)nh * HD + vd) * TS + vkc * 8;
    const int ldsoff = w << 9;

    #define STAGE(buf, kt) do {                                   \
        size_t ko = (size_t)(kt) * (32 * HD);                     \
        int    vo = (kt) * 32;                                    \
        GL_LDS16(khs + ko, &Kh[buf][ldsoff]);                     \
        GL_LDS16(kls + ko, &Kl[buf][ldsoff]);                     \
        GL_LDS16(vhs + vo, &Vh[buf][ldsoff]);                     \
        GL_LDS16(vls + vo, &Vl[buf][ldsoff]);                     \
    } while (0)

    const int n2 = nh / NH, hh2 = nh % NH;

    for (int ph = 0; ph < 2; ++ph) {
        const int qt = ph ? qtB : qtA;
        const int qrow0 = qt * 128 + w * 32;
        const int nkt = 4 * qt + 4;
        const int wave_last = 4 * qt + w;

        // ---- Q fragments (B-operand; same addressing as before) ----
        bf16x8 qh[2][2], ql[2][2];
        #pragma unroll
        for (int mf = 0; mf < 2; ++mf)
            #pragma unroll
            for (int kf = 0; kf < 2; ++kf) {
                size_t a = ((size_t)nh * TS + qrow0 + mf * 16 + c) * HD + kf * 32 + g * 8;
                qh[mf][kf] = *(const bf16x8*)&Qhi[a];
                ql[mf][kf] = *(const bf16x8*)&Qlo[a];
            }

        f32x4 o[4][2];                 // [vnf(d)][mf(q)]  O^T: row d, col q
        float mr[2], lr[2];
        #pragma unroll
        for (int vnf = 0; vnf < 4; ++vnf)
            #pragma unroll
            for (int mf = 0; mf < 2; ++mf) o[vnf][mf] = (f32x4){0.f, 0.f, 0.f, 0.f};
        mr[0] = mr[1] = -INFINITY;
        lr[0] = lr[1] = 0.f;

        STAGE(0, 0);
        __syncthreads();
        int buf = 0;

        for (int kt = 0; kt < nkt; ++kt) {
            if (kt + 1 < nkt) STAGE(buf ^ 1, kt + 1);

            if (kt <= wave_last) {
                // ---- K fragments (A-operand; same addressing) ----
                bf16x8 khf[2][2], klf[2][2];
                #pragma unroll
                for (int knf = 0; knf < 2; ++knf)
                    #pragma unroll
                    for (int kf = 0; kf < 2; ++kf) {
                        int key = knf * 16 + c;
                        int off = key * 64 + ((kf * 32 + g * 8) ^ ((key & 7) << 3));
                        khf[knf][kf] = *(const bf16x8*)&Kh[buf][off];
                        klf[knf][kf] = *(const bf16x8*)&Kl[buf][off];
                    }

                // ---- S^T = K Q^T (3-term hi/lo) ----
                f32x4 st[2][2];        // [knf][mf]
                __builtin_amdgcn_s_setprio(1);
                #pragma unroll
                for (int knf = 0; knf < 2; ++knf)
                    #pragma unroll
                    for (int mf = 0; mf < 2; ++mf) {
                        f32x4 a2 = (f32x4){0.f, 0.f, 0.f, 0.f};
                        #pragma unroll
                        for (int kf = 0; kf < 2; ++kf) {
                            a2 = __builtin_amdgcn_mfma_f32_16x16x32_bf16(khf[knf][kf], qh[mf][kf], a2, 0, 0, 0);
                            a2 = __builtin_amdgcn_mfma_f32_16x16x32_bf16(khf[knf][kf], ql[mf][kf], a2, 0, 0, 0);
                            a2 = __builtin_amdgcn_mfma_f32_16x16x32_bf16(klf[knf][kf], qh[mf][kf], a2, 0, 0, 0);
                        }
                        st[knf][mf] = a2;
                    }
                __builtin_amdgcn_s_setprio(0);

                // ---- causal mask on diagonal tile ----
                if (kt == wave_last) {
                    #pragma unroll
                    for (int knf = 0; knf < 2; ++knf)
                        #pragma unroll
                        for (int mf = 0; mf < 2; ++mf)
                            #pragma unroll
                            for (int r = 0; r < 4; ++r) {
                                int key = kt * 32 + knf * 16 + 4 * g + r;
                                int q   = qrow0 + mf * 16 + c;
                                if (key > q) st[knf][mf][r] = -INFINITY;
                            }
                }

                // ---- online softmax: per-lane scalars ----
                #pragma unroll
                for (int mf = 0; mf < 2; ++mf) {
                    float tm = st[0][mf][0];
                    #pragma unroll
                    for (int r = 1; r < 4; ++r) tm = fmaxf(tm, st[0][mf][r]);
                    #pragma unroll
                    for (int r = 0; r < 4; ++r) tm = fmaxf(tm, st[1][mf][r]);
                    tm = fmaxf(tm, __shfl_xor(tm, 16));
                    tm = fmaxf(tm, __shfl_xor(tm, 32));
                    float nm   = fmaxf(mr[mf], tm);
                    float corr = __expf(mr[mf] - nm);
                    mr[mf] = nm;

                    float rs = 0.f;
                    uint wrd[2][2];
                    #pragma unroll
                    for (int knf = 0; knf < 2; ++knf)
                        #pragma unroll
                        for (int h = 0; h < 2; ++h) {
                            float p0 = __expf(st[knf][mf][2*h]   - nm);
                            float p1 = __expf(st[knf][mf][2*h+1] - nm);
                            ushort b0 = f2bf(p0), b1 = f2bf(p1);
                            wrd[knf][h] = (uint)b0 | ((uint)b1 << 16);
                            rs += bf2f(b0) + bf2f(b1);
                        }
                    rs += __shfl_xor(rs, 16);
                    rs += __shfl_xor(rs, 32);
                    lr[mf] = lr[mf] * corr + rs;
                    #pragma unroll
                    for (int vnf = 0; vnf < 4; ++vnf)
                        #pragma unroll
                        for (int r = 0; r < 4; ++r) o[vnf][mf][r] *= corr;

                    // P^T relayout: write words [q=c][8knf+2g+h]
                    uint* pl = &Pw[w][mf][0];
                    #pragma unroll
                    for (int knf = 0; knf < 2; ++knf)
                        #pragma unroll
                        for (int h = 0; h < 2; ++h)
                            pl[c * 20 + 8 * knf + 2 * g + h] = wrd[knf][h];
                }

                // ---- read P^T B-frags: keys {8g..8g+7} for col q=c ----
                bf16x8 pa[2];
                #pragma unroll
                for (int mf = 0; mf < 2; ++mf)
                    pa[mf] = *(const bf16x8*)&Pw[w][mf][c * 20 + 4 * g];

                // ---- V fragments (A-operand; same addressing) ----
                bf16x8 vhf[4], vlf[4];
                #pragma unroll
                for (int vnf = 0; vnf < 4; ++vnf) {
                    int d = vnf * 16 + c;
                    int off = d * 32 + ((g ^ ((d >> 1) & 3)) << 3);
                    vhf[vnf] = *(const bf16x8*)&Vh[buf][off];
                    vlf[vnf] = *(const bf16x8*)&Vl[buf][off];
                }
                // ---- O^T += V^T P^T (V hi/lo) ----
                __builtin_amdgcn_s_setprio(1);
                #pragma unroll
                for (int vnf = 0; vnf < 4; ++vnf)
                    #pragma unroll
                    for (int mf = 0; mf < 2; ++mf) {
                        o[vnf][mf] = __builtin_amdgcn_mfma_f32_16x16x32_bf16(vhf[vnf], pa[mf], o[vnf][mf], 0, 0, 0);
                        o[vnf][mf] = __builtin_amdgcn_mfma_f32_16x16x32_bf16(vlf[vnf], pa[mf], o[vnf][mf], 0, 0, 0);
                    }
                __builtin_amdgcn_s_setprio(0);
            }

            __syncthreads();
            buf ^= 1;
        }

        // ---- epilogue: O^T/L -> ctx hi/lo bf16 [N,T,D], 4-d runs ----
        #pragma unroll
        for (int mf = 0; mf < 2; ++mf) {
            float inv = 1.0f / lr[mf];
            int q = qrow0 + mf * 16 + c;
            size_t rowb = ((size_t)(n2 * TS + q)) * DM + hh2 * HD;
            #pragma unroll
            for (int vnf = 0; vnf < 4; ++vnf) {
                ushort4 hv, lv;
                #pragma unroll
                for (int r = 0; r < 4; ++r) {
                    float v = o[vnf][mf][r] * inv;
                    ushort h = f2bf(v);
                    ((ushort*)&hv)[r] = h;
                    ((ushort*)&lv)[r] = f2bf(v - bf2f(h));
                }
                *(ushort4*)&ctxhi[rowb + vnf * 16 + 4 * g] = hv;
                *(ushort4*)&ctxlo[rowb + vnf * 16 + 4 * g] = lv;
            }
        }
    }
    #undef STAGE
}

// ---------------- out projection, MFMA hi/lo (unchanged r5) ----------------
__global__ __launch_bounds__(256) void outproj_mfma_k(
    const ushort* __restrict__ Ahi_g, const ushort* __restrict__ Alo_g,
    const float* __restrict__ W, float* __restrict__ out) {
    __shared__ __align__(16) char smem[49152];
    ushort* Ah = (ushort*)smem;
    ushort* Al = Ah + 128 * 64;
    ushort* Bh = Al + 128 * 64;
    ushort* Bl = Bh + 64 * 64;

    const int tid  = threadIdx.x;
    const int w    = tid >> 6;
    const int lane = tid & 63;
    const int g    = lane >> 4;
    const int c    = lane & 15;
    const int row0 = blockIdx.x * 128;
    const int col0 = blockIdx.y * 64;

    f32x4 acc[2][4];
    #pragma unroll
    for (int mf = 0; mf < 2; ++mf)
        #pragma unroll
        for (int nf = 0; nf < 4; ++nf) acc[mf][nf] = (f32x4){0.f, 0.f, 0.f, 0.f};

    const int srow  = tid >> 1;
    const int shalf = tid & 1;
    const int fra   = (srow ^ (srow >> 3)) & 7;

    for (int kt = 0; kt < 6; ++kt) {
        const int k0 = kt * 64;
        bf16x8 ahv[4], alv[4];
        {
            const ushort* ap = &Ahi_g[(size_t)(row0 + srow) * DM + k0 + shalf * 32];
            const ushort* lp = &Alo_g[(size_t)(row0 + srow) * DM + k0 + shalf * 32];
            #pragma unroll
            for (int j = 0; j < 4; ++j) {
                ahv[j] = *(const bf16x8*)(ap + j * 8);
                alv[j] = *(const bf16x8*)(lp + j * 8);
            }
        }
        float wv[32];
        if (tid < 128) {
            const float* wp = &W[(size_t)(col0 + srow) * DM + k0 + shalf * 32];
            #pragma unroll
            for (int j = 0; j < 8; ++j) {
                float4 t4 = *(const float4*)(wp + j * 4);
                wv[j*4+0] = t4.x; wv[j*4+1] = t4.y; wv[j*4+2] = t4.z; wv[j*4+3] = t4.w;
            }
        }
        __syncthreads();
        #pragma unroll
        for (int j = 0; j < 4; ++j) {
            int off = srow * 64 + (((shalf * 4 + j) ^ fra) << 3);
            *(bf16x8*)&Ah[off] = ahv[j];
            *(bf16x8*)&Al[off] = alv[j];
        }
        if (tid < 128) {
            #pragma unroll
            for (int ch4 = 0; ch4 < 4; ++ch4) {
                bf16x8 hv, lv;
                #pragma unroll
                for (int e = 0; e < 8; ++e) {
                    float f = wv[ch4 * 8 + e];
                    ushort h = f2bf(f);
                    hv[e] = (short)h;
                    lv[e] = (short)f2bf(f - bf2f(h));
                }
                int off = srow * 64 + (((shalf * 4 + ch4) ^ fra) << 3);
                *(bf16x8*)&Bh[off] = hv;
                *(bf16x8*)&Bl[off] = lv;
            }
        }
        __syncthreads();
        bf16x8 ahf[2][2], alf[2][2], bhf[4][2], blf[4][2];
        #pragma unroll
        for (int mf = 0; mf < 2; ++mf) {
            int arow = w * 32 + mf * 16 + c;
            int fa = (arow ^ (arow >> 3)) & 7;
            #pragma unroll
            for (int kf = 0; kf < 2; ++kf) {
                int off = arow * 64 + (((kf * 4 + g) ^ fa) << 3);
                ahf[mf][kf] = *(const bf16x8*)&Ah[off];
                alf[mf][kf] = *(const bf16x8*)&Al[off];
            }
        }
        #pragma unroll
        for (int nf = 0; nf < 4; ++nf) {
            int brow = nf * 16 + c;
            int fb = (brow ^ (brow >> 3)) & 7;
            #pragma unroll
            for (int kf = 0; kf < 2; ++kf) {
                int off = brow * 64 + (((kf * 4 + g) ^ fb) << 3);
                bhf[nf][kf] = *(const bf16x8*)&Bh[off];
                blf[nf][kf] = *(const bf16x8*)&Bl[off];
            }
        }
        __builtin_amdgcn_s_setprio(1);
        #pragma unroll
        for (int mf = 0; mf < 2; ++mf)
            #pragma unroll
            for (int nf = 0; nf < 4; ++nf)
                #pragma unroll
                for (int kf = 0; kf < 2; ++kf) {
                    acc[mf][nf] = __builtin_amdgcn_mfma_f32_16x16x32_bf16(ahf[mf][kf], bhf[nf][kf], acc[mf][nf], 0, 0, 0);
                    acc[mf][nf] = __builtin_amdgcn_mfma_f32_16x16x32_bf16(alf[mf][kf], bhf[nf][kf], acc[mf][nf], 0, 0, 0);
                    acc[mf][nf] = __builtin_amdgcn_mfma_f32_16x16x32_bf16(ahf[mf][kf], blf[nf][kf], acc[mf][nf], 0, 0, 0);
                }
        __builtin_amdgcn_s_setprio(0);
    }

    #pragma unroll
    for (int mf = 0; mf < 2; ++mf)
        #pragma unroll
        for (int r = 0; r < 4; ++r) {
            int row = row0 + w * 32 + mf * 16 + 4 * g + r;
            #pragma unroll
            for (int nf = 0; nf < 4; ++nf)
                out[(size_t)row * DM + col0 + nf * 16 + c] = acc[mf][nf][r];
        }
}

extern "C" void kernel_launch(void* const* d_in, const int* in_sizes, int n_in,
                              void* d_out, int out_size, void* d_ws, size_t ws_size,
                              hipStream_t stream) {
    const float* x    = (const float*)d_in[0];
    const float* Wqkv = (const float*)d_in[1];
    const float* Wout = (const float*)d_in[2];
    float* out = (float*)d_out;

    const size_t NHT = (size_t)NB * NH * TS * HD;
    char* ws = (char*)d_ws;
    float* cosT = (float*)ws;                        ws += TS * HD * 4;
    float* sinT = (float*)ws;                        ws += TS * HD * 4;
    ushort* Qhi = (ushort*)ws;                       ws += NHT * 2;
    ushort* Qlo = (ushort*)ws;                       ws += NHT * 2;
    ushort* Khi = (ushort*)ws;                       ws += NHT * 2;
    ushort* Klo = (ushort*)ws;                       ws += NHT * 2;
    ushort* Vthi = (ushort*)ws;                      ws += NHT * 2;
    ushort* Vtlo = (ushort*)ws;                      ws += NHT * 2;
    ushort* ctxhi = (ushort*)ws;                     ws += (size_t)MROWS * DM * 2;
    ushort* ctxlo = (ushort*)ws;                     ws += (size_t)MROWS * DM * 2;

    rope_table_k<<<(TS * HD) / 256, 256, 0, stream>>>(cosT, sinT);
    qkv_mfma_k<<<dim3(MROWS / 128, E3 / 64), 256, 0, stream>>>(
        x, Wqkv, cosT, sinT, Qhi, Qlo, Khi, Klo, Vthi, Vtlo);
    flash_mfma_k<<<384, 256, 0, stream>>>(
        Qhi, Qlo, Khi, Klo, Vthi, Vtlo, ctxhi, ctxlo);
    outproj_mfma_k<<<dim3(MROWS / 128, DM / 64), 256, 0, stream>>>(
        ctxhi, ctxlo, Wout, out);
}

// Round 7
// 330.875 us; speedup vs baseline: 2.0837x; 1.1267x over previous
//
#include <hip/hip_runtime.h>
#include <math.h>

#define NB 8
#define TS 2048
#define DM 384
#define NH 6
#define HD 64
#define E3 1152
#define MROWS (NB*TS)

typedef __attribute__((ext_vector_type(8))) short bf16x8;
typedef __attribute__((ext_vector_type(4))) float f32x4;

__device__ __forceinline__ ushort f2bf(float f) {
    uint u = __float_as_uint(f);
    uint r = (u + 0x7FFFu + ((u >> 16) & 1u)) >> 16;
    return (ushort)r;
}
__device__ __forceinline__ float bf2f(ushort h) {
    return __uint_as_float(((uint)h) << 16);
}

#define GL_LDS16(gp, lp) \
  __builtin_amdgcn_global_load_lds((const __attribute__((address_space(1))) uint32_t*)(gp), \
                                   (__attribute__((address_space(3))) uint32_t*)(lp), 16, 0, 0)

// ---------------- hi/lo bf16 split of X, Wqkv, Wout ----------------
__global__ void split_hilo_k(const float* __restrict__ X,
                             const float* __restrict__ Wq,
                             const float* __restrict__ Wo,
                             ushort* __restrict__ Xhi, ushort* __restrict__ Xlo,
                             ushort* __restrict__ Wqhi, ushort* __restrict__ Wqlo,
                             ushort* __restrict__ Wohi, ushort* __restrict__ Wolo) {
    const int NX = MROWS * DM / 4;
    const int NQ = E3 * DM / 4;
    const int NO = DM * DM / 4;
    const int total = NX + NQ + NO;
    for (int idx = blockIdx.x * 256 + threadIdx.x; idx < total; idx += gridDim.x * 256) {
        const float* src; ushort* dh; ushort* dl; int i;
        if (idx < NX)           { src = X;  dh = Xhi;  dl = Xlo;  i = idx; }
        else if (idx < NX + NQ) { src = Wq; dh = Wqhi; dl = Wqlo; i = idx - NX; }
        else                    { src = Wo; dh = Wohi; dl = Wolo; i = idx - NX - NQ; }
        float4 v = *(const float4*)&src[(size_t)i * 4];
        float f[4] = {v.x, v.y, v.z, v.w};
        ushort4 hv, lv;
        #pragma unroll
        for (int j = 0; j < 4; ++j) {
            ushort h = f2bf(f[j]);
            ((ushort*)&hv)[j] = h;
            ((ushort*)&lv)[j] = f2bf(f[j] - bf2f(h));
        }
        *(ushort4*)&dh[(size_t)i * 4] = hv;
        *(ushort4*)&dl[(size_t)i * 4] = lv;
    }
}

// ---------------- RoPE cos/sin table: [T, 64] ----------------
__global__ void rope_table_k(float* __restrict__ cosT, float* __restrict__ sinT) {
    int i = blockIdx.x * 256 + threadIdx.x;
    if (i >= TS * HD) return;
    int t   = i >> 6;
    int idx = i & 63;
    int fi  = idx & 31;
    float inv = expf(-(float)fi * (logf(10000.0f) * (1.0f / 32.0f)));
    float ang = (float)t * inv;
    cosT[i] = cosf(ang);
    sinT[i] = sinf(ang);
}

// ---------------- QKV GEMM, MFMA hi/lo from pre-split bf16, fused RoPE ----------------
__global__ __launch_bounds__(256) void qkv_mfma_k(
    const ushort* __restrict__ Xhi_g, const ushort* __restrict__ Xlo_g,
    const ushort* __restrict__ Whi_g, const ushort* __restrict__ Wlo_g,
    const float* __restrict__ cosT, const float* __restrict__ sinT,
    ushort* __restrict__ Qhi, ushort* __restrict__ Qlo,
    ushort* __restrict__ Khi, ushort* __restrict__ Klo,
    ushort* __restrict__ Vthi, ushort* __restrict__ Vtlo) {
    __shared__ __align__(16) char smem[49152];
    ushort* Ah = (ushort*)smem;
    ushort* Al = Ah + 128 * 64;
    ushort* Bh = Al + 128 * 64;
    ushort* Bl = Bh + 64 * 64;
    float*  VT = (float*)smem;

    const int tid  = threadIdx.x;
    const int w    = tid >> 6;
    const int lane = tid & 63;
    const int g    = lane >> 4;
    const int c    = lane & 15;
    const int row0 = blockIdx.x * 128;
    const int col0 = blockIdx.y * 64;

    f32x4 acc[2][4];
    #pragma unroll
    for (int mf = 0; mf < 2; ++mf)
        #pragma unroll
        for (int nf = 0; nf < 4; ++nf) acc[mf][nf] = (f32x4){0.f, 0.f, 0.f, 0.f};

    const int srow  = tid >> 1;
    const int shalf = tid & 1;
    const int fra   = (srow ^ (srow >> 3)) & 7;

    for (int kt = 0; kt < 6; ++kt) {
        const int k0 = kt * 64;
        bf16x8 xav[4], xlv[4];
        {
            const ushort* ap = &Xhi_g[(size_t)(row0 + srow) * DM + k0 + shalf * 32];
            const ushort* lp = &Xlo_g[(size_t)(row0 + srow) * DM + k0 + shalf * 32];
            #pragma unroll
            for (int j = 0; j < 4; ++j) {
                xav[j] = *(const bf16x8*)(ap + j * 8);
                xlv[j] = *(const bf16x8*)(lp + j * 8);
            }
        }
        bf16x8 wav[4], wlv[4];
        if (tid < 128) {
            const ushort* ap = &Whi_g[(size_t)(col0 + srow) * DM + k0 + shalf * 32];
            const ushort* lp = &Wlo_g[(size_t)(col0 + srow) * DM + k0 + shalf * 32];
            #pragma unroll
            for (int j = 0; j < 4; ++j) {
                wav[j] = *(const bf16x8*)(ap + j * 8);
                wlv[j] = *(const bf16x8*)(lp + j * 8);
            }
        }
        __syncthreads();
        #pragma unroll
        for (int j = 0; j < 4; ++j) {
            int off = srow * 64 + (((shalf * 4 + j) ^ fra) << 3);
            *(bf16x8*)&Ah[off] = xav[j];
            *(bf16x8*)&Al[off] = xlv[j];
        }
        if (tid < 128) {
            #pragma unroll
            for (int j = 0; j < 4; ++j) {
                int off = srow * 64 + (((shalf * 4 + j) ^ fra) << 3);
                *(bf16x8*)&Bh[off] = wav[j];
                *(bf16x8*)&Bl[off] = wlv[j];
            }
        }
        __syncthreads();
        bf16x8 ahf[2][2], alf[2][2], bhf[4][2], blf[4][2];
        #pragma unroll
        for (int mf = 0; mf < 2; ++mf) {
            int arow = w * 32 + mf * 16 + c;
            int fa = (arow ^ (arow >> 3)) & 7;
            #pragma unroll
            for (int kf = 0; kf < 2; ++kf) {
                int off = arow * 64 + (((kf * 4 + g) ^ fa) << 3);
                ahf[mf][kf] = *(const bf16x8*)&Ah[off];
                alf[mf][kf] = *(const bf16x8*)&Al[off];
            }
        }
        #pragma unroll
        for (int nf = 0; nf < 4; ++nf) {
            int brow = nf * 16 + c;
            int fb = (brow ^ (brow >> 3)) & 7;
            #pragma unroll
            for (int kf = 0; kf < 2; ++kf) {
                int off = brow * 64 + (((kf * 4 + g) ^ fb) << 3);
                bhf[nf][kf] = *(const bf16x8*)&Bh[off];
                blf[nf][kf] = *(const bf16x8*)&Bl[off];
            }
        }
        __builtin_amdgcn_s_setprio(1);
        #pragma unroll
        for (int mf = 0; mf < 2; ++mf)
            #pragma unroll
            for (int nf = 0; nf < 4; ++nf)
                #pragma unroll
                for (int kf = 0; kf < 2; ++kf) {
                    acc[mf][nf] = __builtin_amdgcn_mfma_f32_16x16x32_bf16(ahf[mf][kf], bhf[nf][kf], acc[mf][nf], 0, 0, 0);
                    acc[mf][nf] = __builtin_amdgcn_mfma_f32_16x16x32_bf16(alf[mf][kf], bhf[nf][kf], acc[mf][nf], 0, 0, 0);
                    acc[mf][nf] = __builtin_amdgcn_mfma_f32_16x16x32_bf16(ahf[mf][kf], blf[nf][kf], acc[mf][nf], 0, 0, 0);
                }
        __builtin_amdgcn_s_setprio(0);
    }

    const int which = blockIdx.y / 6;
    const int hh    = blockIdx.y % 6;
    const int n     = row0 >> 11;
    const int nh    = n * NH + hh;

    if (which < 2) {
        ushort* dhi = (which == 0) ? Qhi : Khi;
        ushort* dlo = (which == 0) ? Qlo : Klo;
        const float qs = (which == 0) ? 0.125f : 1.0f;
        #pragma unroll
        for (int mf = 0; mf < 2; ++mf)
            #pragma unroll
            for (int r = 0; r < 4; ++r) {
                int t = (row0 + w * 32 + mf * 16 + 4 * g + r) & (TS - 1);
                #pragma unroll
                for (int nf = 0; nf < 4; ++nf) {
                    int p = nf * 16 + c;
                    float a = acc[mf][nf][r];
                    float b = acc[mf][nf ^ 2][r];
                    float cc = cosT[t * HD + p];
                    float ss = sinT[t * HD + p];
                    float v = (nf < 2) ? (a * cc - b * ss) : (a * cc + b * ss);
                    v *= qs;
                    ushort h = f2bf(v);
                    size_t addr = ((size_t)nh * TS + t) * HD + p;
                    dhi[addr] = h;
                    dlo[addr] = f2bf(v - bf2f(h));
                }
            }
    } else {
        __syncthreads();
        #pragma unroll
        for (int mf = 0; mf < 2; ++mf)
            #pragma unroll
            for (int nf = 0; nf < 4; ++nf)
                #pragma unroll
                for (int r = 0; r < 4; ++r)
                    VT[(nf * 16 + c) * 132 + w * 32 + mf * 16 + 4 * g + r] = acc[mf][nf][r];
        __syncthreads();
        int d = tid >> 2, seg = (tid & 3) * 32;
        int t0 = row0 & (TS - 1);
        size_t vbase = ((size_t)nh * HD + d) * TS + t0 + seg;
        #pragma unroll
        for (int j = 0; j < 4; ++j) {
            bf16x8 hv, lv;
            #pragma unroll
            for (int e = 0; e < 8; ++e) {
                float f = VT[d * 132 + seg + j * 8 + e];
                ushort h = f2bf(f);
                hv[e] = (short)h;
                lv[e] = (short)f2bf(f - bf2f(h));
            }
            *(bf16x8*)&Vthi[vbase + j * 8] = hv;
            *(bf16x8*)&Vtlo[vbase + j * 8] = lv;
        }
    }
}

// ---------------- MFMA flash attention, swapped-operand softmax ----------------
__global__ __launch_bounds__(256) void flash_mfma_k(
    const ushort* __restrict__ Qhi, const ushort* __restrict__ Qlo,
    const ushort* __restrict__ Khi_g, const ushort* __restrict__ Klo_g,
    const ushort* __restrict__ Vthi_g, const ushort* __restrict__ Vtlo_g,
    ushort* __restrict__ ctxhi, ushort* __restrict__ ctxlo) {
    __shared__ ushort Kh[2][2048], Kl[2][2048];
    __shared__ ushort Vh[2][2048], Vl[2][2048];
    __shared__ uint   Pw[4][2][320];

    const int tid  = threadIdx.x;
    const int w    = tid >> 6;
    const int lane = tid & 63;
    const int g    = lane >> 4;
    const int c    = lane & 15;

    const int b   = blockIdx.x;
    const int xcd = b & 7;
    const int li  = b >> 3;
    const int nh  = xcd * 6 + li / 8;
    const int pr  = li % 8;
    const int qtA = 15 - pr, qtB = pr;

    const int kkey = tid >> 3, kcid = tid & 7;
    const ushort* khs = Khi_g + (size_t)nh * TS * HD + (size_t)kkey * HD + ((kcid ^ (kkey & 7)) << 3);
    const ushort* kls = Klo_g + (size_t)nh * TS * HD + (size_t)kkey * HD + ((kcid ^ (kkey & 7)) << 3);
    const int vd = tid >> 2, vkc = (tid & 3) ^ ((vd >> 1) & 3);
    const ushort* vhs = Vthi_g + ((size_t)nh * HD + vd) * TS + vkc * 8;
    const ushort* vls = Vtlo_g + ((size_t)nh * HD + vd) * TS + vkc * 8;
    const int ldsoff = w << 9;

    #define STAGE(buf, kt) do {                                   \
        size_t ko = (size_t)(kt) * (32 * HD);                     \
        int    vo = (kt) * 32;                                    \
        GL_LDS16(khs + ko, &Kh[buf][ldsoff]);                     \
        GL_LDS16(kls + ko, &Kl[buf][ldsoff]);                     \
        GL_LDS16(vhs + vo, &Vh[buf][ldsoff]);                     \
        GL_LDS16(vls + vo, &Vl[buf][ldsoff]);                     \
    } while (0)

    const int n2 = nh / NH, hh2 = nh % NH;

    for (int ph = 0; ph < 2; ++ph) {
        const int qt = ph ? qtB : qtA;
        const int qrow0 = qt * 128 + w * 32;
        const int nkt = 4 * qt + 4;
        const int wave_last = 4 * qt + w;

        bf16x8 qh[2][2], ql[2][2];
        #pragma unroll
        for (int mf = 0; mf < 2; ++mf)
            #pragma unroll
            for (int kf = 0; kf < 2; ++kf) {
                size_t a = ((size_t)nh * TS + qrow0 + mf * 16 + c) * HD + kf * 32 + g * 8;
                qh[mf][kf] = *(const bf16x8*)&Qhi[a];
                ql[mf][kf] = *(const bf16x8*)&Qlo[a];
            }

        f32x4 o[4][2];
        float mr[2], lr[2];
        #pragma unroll
        for (int vnf = 0; vnf < 4; ++vnf)
            #pragma unroll
            for (int mf = 0; mf < 2; ++mf) o[vnf][mf] = (f32x4){0.f, 0.f, 0.f, 0.f};
        mr[0] = mr[1] = -INFINITY;
        lr[0] = lr[1] = 0.f;

        STAGE(0, 0);
        __syncthreads();
        int buf = 0;

        for (int kt = 0; kt < nkt; ++kt) {
            if (kt + 1 < nkt) STAGE(buf ^ 1, kt + 1);

            if (kt <= wave_last) {
                bf16x8 khf[2][2], klf[2][2];
                #pragma unroll
                for (int knf = 0; knf < 2; ++knf)
                    #pragma unroll
                    for (int kf = 0; kf < 2; ++kf) {
                        int key = knf * 16 + c;
                        int off = key * 64 + ((kf * 32 + g * 8) ^ ((key & 7) << 3));
                        khf[knf][kf] = *(const bf16x8*)&Kh[buf][off];
                        klf[knf][kf] = *(const bf16x8*)&Kl[buf][off];
                    }

                f32x4 st[2][2];
                __builtin_amdgcn_s_setprio(1);
                #pragma unroll
                for (int knf = 0; knf < 2; ++knf)
                    #pragma unroll
                    for (int mf = 0; mf < 2; ++mf) {
                        f32x4 a2 = (f32x4){0.f, 0.f, 0.f, 0.f};
                        #pragma unroll
                        for (int kf = 0; kf < 2; ++kf) {
                            a2 = __builtin_amdgcn_mfma_f32_16x16x32_bf16(khf[knf][kf], qh[mf][kf], a2, 0, 0, 0);
                            a2 = __builtin_amdgcn_mfma_f32_16x16x32_bf16(khf[knf][kf], ql[mf][kf], a2, 0, 0, 0);
                            a2 = __builtin_amdgcn_mfma_f32_16x16x32_bf16(klf[knf][kf], qh[mf][kf], a2, 0, 0, 0);
                        }
                        st[knf][mf] = a2;
                    }
                __builtin_amdgcn_s_setprio(0);

                if (kt == wave_last) {
                    #pragma unroll
                    for (int knf = 0; knf < 2; ++knf)
                        #pragma unroll
                        for (int mf = 0; mf < 2; ++mf)
                            #pragma unroll
                            for (int r = 0; r < 4; ++r) {
                                int key = kt * 32 + knf * 16 + 4 * g + r;
                                int q   = qrow0 + mf * 16 + c;
                                if (key > q) st[knf][mf][r] = -INFINITY;
                            }
                }

                #pragma unroll
                for (int mf = 0; mf < 2; ++mf) {
                    float tm = st[0][mf][0];
                    #pragma unroll
                    for (int r = 1; r < 4; ++r) tm = fmaxf(tm, st[0][mf][r]);
                    #pragma unroll
                    for (int r = 0; r < 4; ++r) tm = fmaxf(tm, st[1][mf][r]);
                    tm = fmaxf(tm, __shfl_xor(tm, 16));
                    tm = fmaxf(tm, __shfl_xor(tm, 32));
                    // defer-rescale (exact): only rescale when some lane's max grew
                    if (!__all(tm <= mr[mf])) {
                        float nm   = fmaxf(mr[mf], tm);
                        float corr = __expf(mr[mf] - nm);
                        mr[mf] = nm;
                        lr[mf] *= corr;
                        #pragma unroll
                        for (int vnf = 0; vnf < 4; ++vnf)
                            #pragma unroll
                            for (int r = 0; r < 4; ++r) o[vnf][mf][r] *= corr;
                    }
                    const float nm = mr[mf];

                    float rs = 0.f;
                    uint wrd[2][2];
                    #pragma unroll
                    for (int knf = 0; knf < 2; ++knf)
                        #pragma unroll
                        for (int h = 0; h < 2; ++h) {
                            float p0 = __expf(st[knf][mf][2*h]   - nm);
                            float p1 = __expf(st[knf][mf][2*h+1] - nm);
                            ushort b0 = f2bf(p0), b1 = f2bf(p1);
                            wrd[knf][h] = (uint)b0 | ((uint)b1 << 16);
                            rs += bf2f(b0) + bf2f(b1);
                        }
                    rs += __shfl_xor(rs, 16);
                    rs += __shfl_xor(rs, 32);
                    lr[mf] += rs;

                    uint* pl = &Pw[w][mf][0];
                    #pragma unroll
                    for (int knf = 0; knf < 2; ++knf)
                        #pragma unroll
                        for (int h = 0; h < 2; ++h)
                            pl[c * 20 + 8 * knf + 2 * g + h] = wrd[knf][h];
                }

                bf16x8 pa[2];
                #pragma unroll
                for (int mf = 0; mf < 2; ++mf)
                    pa[mf] = *(const bf16x8*)&Pw[w][mf][c * 20 + 4 * g];

                bf16x8 vhf[4], vlf[4];
                #pragma unroll
                for (int vnf = 0; vnf < 4; ++vnf) {
                    int d = vnf * 16 + c;
                    int off = d * 32 + ((g ^ ((d >> 1) & 3)) << 3);
                    vhf[vnf] = *(const bf16x8*)&Vh[buf][off];
                    vlf[vnf] = *(const bf16x8*)&Vl[buf][off];
                }
                __builtin_amdgcn_s_setprio(1);
                #pragma unroll
                for (int vnf = 0; vnf < 4; ++vnf)
                    #pragma unroll
                    for (int mf = 0; mf < 2; ++mf) {
                        o[vnf][mf] = __builtin_amdgcn_mfma_f32_16x16x32_bf16(vhf[vnf], pa[mf], o[vnf][mf], 0, 0, 0);
                        o[vnf][mf] = __builtin_amdgcn_mfma_f32_16x16x32_bf16(vlf[vnf], pa[mf], o[vnf][mf], 0, 0, 0);
                    }
                __builtin_amdgcn_s_setprio(0);
            }

            __syncthreads();
            buf ^= 1;
        }

        #pragma unroll
        for (int mf = 0; mf < 2; ++mf) {
            float inv = 1.0f / lr[mf];
            int q = qrow0 + mf * 16 + c;
            size_t rowb = ((size_t)(n2 * TS + q)) * DM + hh2 * HD;
            #pragma unroll
            for (int vnf = 0; vnf < 4; ++vnf) {
                ushort4 hv, lv;
                #pragma unroll
                for (int r = 0; r < 4; ++r) {
                    float v = o[vnf][mf][r] * inv;
                    ushort h = f2bf(v);
                    ((ushort*)&hv)[r] = h;
                    ((ushort*)&lv)[r] = f2bf(v - bf2f(h));
                }
                *(ushort4*)&ctxhi[rowb + vnf * 16 + 4 * g] = hv;
                *(ushort4*)&ctxlo[rowb + vnf * 16 + 4 * g] = lv;
            }
        }
    }
    #undef STAGE
}

// ---------------- out projection, MFMA hi/lo, pre-split W ----------------
__global__ __launch_bounds__(256) void outproj_mfma_k(
    const ushort* __restrict__ Ahi_g, const ushort* __restrict__ Alo_g,
    const ushort* __restrict__ Whi_g, const ushort* __restrict__ Wlo_g,
    float* __restrict__ out) {
    __shared__ __align__(16) char smem[49152];
    ushort* Ah = (ushort*)smem;
    ushort* Al = Ah + 128 * 64;
    ushort* Bh = Al + 128 * 64;
    ushort* Bl = Bh + 64 * 64;

    const int tid  = threadIdx.x;
    const int w    = tid >> 6;
    const int lane = tid & 63;
    const int g    = lane >> 4;
    const int c    = lane & 15;
    const int row0 = blockIdx.x * 128;
    const int col0 = blockIdx.y * 64;

    f32x4 acc[2][4];
    #pragma unroll
    for (int mf = 0; mf < 2; ++mf)
        #pragma unroll
        for (int nf = 0; nf < 4; ++nf) acc[mf][nf] = (f32x4){0.f, 0.f, 0.f, 0.f};

    const int srow  = tid >> 1;
    const int shalf = tid & 1;
    const int fra   = (srow ^ (srow >> 3)) & 7;

    for (int kt = 0; kt < 6; ++kt) {
        const int k0 = kt * 64;
        bf16x8 ahv[4], alv[4];
        {
            const ushort* ap = &Ahi_g[(size_t)(row0 + srow) * DM + k0 + shalf * 32];
            const ushort* lp = &Alo_g[(size_t)(row0 + srow) * DM + k0 + shalf * 32];
            #pragma unroll
            for (int j = 0; j < 4; ++j) {
                ahv[j] = *(const bf16x8*)(ap + j * 8);
                alv[j] = *(const bf16x8*)(lp + j * 8);
            }
        }
        bf16x8 wav[4], wlv[4];
        if (tid < 128) {
            const ushort* ap = &Whi_g[(size_t)(col0 + srow) * DM + k0 + shalf * 32];
            const ushort* lp = &Wlo_g[(size_t)(col0 + srow) * DM + k0 + shalf * 32];
            #pragma unroll
            for (int j = 0; j < 4; ++j) {
                wav[j] = *(const bf16x8*)(ap + j * 8);
                wlv[j] = *(const bf16x8*)(lp + j * 8);
            }
        }
        __syncthreads();
        #pragma unroll
        for (int j = 0; j < 4; ++j) {
            int off = srow * 64 + (((shalf * 4 + j) ^ fra) << 3);
            *(bf16x8*)&Ah[off] = ahv[j];
            *(bf16x8*)&Al[off] = alv[j];
        }
        if (tid < 128) {
            #pragma unroll
            for (int j = 0; j < 4; ++j) {
                int off = srow * 64 + (((shalf * 4 + j) ^ fra) << 3);
                *(bf16x8*)&Bh[off] = wav[j];
                *(bf16x8*)&Bl[off] = wlv[j];
            }
        }
        __syncthreads();
        bf16x8 ahf[2][2], alf[2][2], bhf[4][2], blf[4][2];
        #pragma unroll
        for (int mf = 0; mf < 2; ++mf) {
            int arow = w * 32 + mf * 16 + c;
            int fa = (arow ^ (arow >> 3)) & 7;
            #pragma unroll
            for (int kf = 0; kf < 2; ++kf) {
                int off = arow * 64 + (((kf * 4 + g) ^ fa) << 3);
                ahf[mf][kf] = *(const bf16x8*)&Ah[off];
                alf[mf][kf] = *(const bf16x8*)&Al[off];
            }
        }
        #pragma unroll
        for (int nf = 0; nf < 4; ++nf) {
            int brow = nf * 16 + c;
            int fb = (brow ^ (brow >> 3)) & 7;
            #pragma unroll
            for (int kf = 0; kf < 2; ++kf) {
                int off = brow * 64 + (((kf * 4 + g) ^ fb) << 3);
                bhf[nf][kf] = *(const bf16x8*)&Bh[off];
                blf[nf][kf] = *(const bf16x8*)&Bl[off];
            }
        }
        __builtin_amdgcn_s_setprio(1);
        #pragma unroll
        for (int mf = 0; mf < 2; ++mf)
            #pragma unroll
            for (int nf = 0; nf < 4; ++nf)
                #pragma unroll
                for (int kf = 0; kf < 2; ++kf) {
                    acc[mf][nf] = __builtin_amdgcn_mfma_f32_16x16x32_bf16(ahf[mf][kf], bhf[nf][kf], acc[mf][nf], 0, 0, 0);
                    acc[mf][nf] = __builtin_amdgcn_mfma_f32_16x16x32_bf16(alf[mf][kf], bhf[nf][kf], acc[mf][nf], 0, 0, 0);
                    acc[mf][nf] = __builtin_amdgcn_mfma_f32_16x16x32_bf16(ahf[mf][kf], blf[nf][kf], acc[mf][nf], 0, 0, 0);
                }
        __builtin_amdgcn_s_setprio(0);
    }

    #pragma unroll
    for (int mf = 0; mf < 2; ++mf)
        #pragma unroll
        for (int r = 0; r < 4; ++r) {
            int row = row0 + w * 32 + mf * 16 + 4 * g + r;
            #pragma unroll
            for (int nf = 0; nf < 4; ++nf)
                out[(size_t)row * DM + col0 + nf * 16 + c] = acc[mf][nf][r];
        }
}

extern "C" void kernel_launch(void* const* d_in, const int* in_sizes, int n_in,
                              void* d_out, int out_size, void* d_ws, size_t ws_size,
                              hipStream_t stream) {
    const float* x    = (const float*)d_in[0];
    const float* Wqkv = (const float*)d_in[1];
    const float* Wout = (const float*)d_in[2];
    float* out = (float*)d_out;

    const size_t NHT = (size_t)NB * NH * TS * HD;   // 6291456 == MROWS*DM
    char* ws = (char*)d_ws;
    float* cosT = (float*)ws;                        ws += TS * HD * 4;
    float* sinT = (float*)ws;                        ws += TS * HD * 4;
    ushort* Qhi = (ushort*)ws;                       ws += NHT * 2;
    ushort* Qlo = (ushort*)ws;                       ws += NHT * 2;
    ushort* Khi = (ushort*)ws;                       ws += NHT * 2;
    ushort* Klo = (ushort*)ws;                       ws += NHT * 2;
    ushort* Vthi = (ushort*)ws;                      ws += NHT * 2;
    ushort* Vtlo = (ushort*)ws;                      ws += NHT * 2;
    ushort* ctxhi = (ushort*)ws;                     ws += (size_t)MROWS * DM * 2;
    ushort* ctxlo = (ushort*)ws;                     ws += (size_t)MROWS * DM * 2;
    ushort* Wqhi = (ushort*)ws;                      ws += (size_t)E3 * DM * 2;
    ushort* Wqlo = (ushort*)ws;                      ws += (size_t)E3 * DM * 2;
    ushort* Wohi = (ushort*)ws;                      ws += (size_t)DM * DM * 2;
    ushort* Wolo = (ushort*)ws;                      ws += (size_t)DM * DM * 2;
    // X planes alias ctx planes (disjoint lifetimes: qkv reads X planes,
    // flash writes ctx planes strictly later in stream order).
    ushort* Xhi = ctxhi;
    ushort* Xlo = ctxlo;

    split_hilo_k<<<2048, 256, 0, stream>>>(x, Wqkv, Wout,
        Xhi, Xlo, Wqhi, Wqlo, Wohi, Wolo);
    rope_table_k<<<(TS * HD) / 256, 256, 0, stream>>>(cosT, sinT);
    qkv_mfma_k<<<dim3(MROWS / 128, E3 / 64), 256, 0, stream>>>(
        Xhi, Xlo, Wqhi, Wqlo, cosT, sinT, Qhi, Qlo, Khi, Klo, Vthi, Vtlo);
    flash_mfma_k<<<384, 256, 0, stream>>>(
        Qhi, Qlo, Khi, Klo, Vthi, Vtlo, ctxhi, ctxlo);
    outproj_mfma_k<<<dim3(MROWS / 128, DM / 6 / 64 * 6), 256, 0, stream>>>(
        ctxhi, ctxlo, Wohi, Wolo, out);
}